// Round 11
// baseline (442.917 us; speedup 1.0000x reference)
//
#include <hip/hip_runtime.h>

#define CDIV(a,b) (((a)+(b)-1)/(b))

// ---------------------------------------------------------------------------
// conv0: 3->96, 64x64 -> 32x32, fully unrolled
// ---------------------------------------------------------------------------
__global__ __launch_bounds__(256) void conv3x3_c3(const float* __restrict__ in,
    const float* __restrict__ w, const float* __restrict__ bias, float* __restrict__ out)
{
    int idx = blockIdx.x * 256 + threadIdx.x;     // 10*96*32*32 = 983040 exact
    int ox = idx & 31; int t = idx >> 5;
    int oy = t & 31;   t >>= 5;
    int co = t % 96;   int b = t / 96;
    float acc = bias[co];
    const float* wp  = w + co * 27;
    const float* ipb = in + (size_t)b * 3 * 64 * 64;
    #pragma unroll
    for (int ci = 0; ci < 3; ++ci) {
        #pragma unroll
        for (int ky = 0; ky < 3; ++ky) {
            int iy = 2 * oy + ky;
            #pragma unroll
            for (int kx = 0; kx < 3; ++kx) {
                int ix = 2 * ox + kx;
                if (iy < 64 && ix < 64)
                    acc = fmaf(wp[ci * 9 + ky * 3 + kx], ipb[(ci * 64 + iy) * 64 + ix], acc);
            }
        }
    }
    out[idx] = fmaxf(acc, 0.f);
}

// ---------------------------------------------------------------------------
// conv1: ci-split-K with LDS staging (unchanged)
// ---------------------------------------------------------------------------
template<int CIN,int COUT,int HIN,int WIN,int SPLITS,int CK,int CO_R>
__global__ __launch_bounds__(256) void conv_splitk_big(const float* __restrict__ in,
    const float* __restrict__ w, float* __restrict__ partial)
{
    constexpr int HOUT = HIN/2, WOUT = WIN/2;
    constexpr int SP = HOUT * WOUT;
    static_assert(SP == 256, "one output px per thread");
    constexpr int HP = HIN + 1, WP = WIN + 2;
    constexpr int CSL = CIN / SPLITS;
    constexpr int NCH = CSL / CK;
    static_assert(CSL % CK == 0, "CK must divide ci slice");
    constexpr int SELEM = CK * HP * WP;
    constexpr int NLD = (SELEM + 255) / 256;
    __shared__ float sb[SELEM];

    const int b = blockIdx.y, s = blockIdx.z;
    const int co_base = blockIdx.x * CO_R;
    const int oy = threadIdx.x >> 4, ox = threadIdx.x & 15;
    const int ci00 = s * CSL;
    const float* inb = in + (size_t)b * CIN * HIN * WIN;

    float rg[NLD];
    auto load_chunk = [&](int ci0) {
        #pragma unroll
        for (int j = 0; j < NLD; ++j) {
            int i = threadIdx.x + j * 256;
            float v = 0.f;
            if (i < SELEM) {
                int c = i % WP; int r = (i / WP) % HP; int cl = i / (WP * HP);
                if (r < HIN && c < WIN) v = inb[((size_t)(ci0 + cl) * HIN + r) * WIN + c];
            }
            rg[j] = v;
        }
    };
    load_chunk(ci00);

    float acc[CO_R] = {};
    for (int ch = 0; ch < NCH; ++ch) {
        #pragma unroll
        for (int j = 0; j < NLD; ++j) {
            int i = threadIdx.x + j * 256;
            if (i < SELEM) sb[i] = rg[j];
        }
        __syncthreads();
        if (ch + 1 < NCH) load_chunk(ci00 + (ch + 1) * CK);

        #pragma unroll
        for (int cl = 0; cl < CK; ++cl) {
            const float* sp = &sb[(cl * HP + 2 * oy) * WP + 2 * ox];
            float x[3][3];
            #pragma unroll
            for (int dy = 0; dy < 3; ++dy) {
                float2 f = *(const float2*)&sp[dy * WP];
                x[dy][0] = f.x; x[dy][1] = f.y; x[dy][2] = sp[dy * WP + 2];
            }
            int ci = ci00 + ch * CK + cl;
            const float* wp = w + ((size_t)co_base * CIN + ci) * 9;
            #pragma unroll
            for (int r = 0; r < CO_R; ++r) {
                const float* wr = wp + (size_t)r * CIN * 9;
                #pragma unroll
                for (int dy = 0; dy < 3; ++dy)
                    #pragma unroll
                    for (int dx = 0; dx < 3; ++dx)
                        acc[r] = fmaf(wr[dy * 3 + dx], x[dy][dx], acc[r]);
            }
        }
        __syncthreads();
    }
    #pragma unroll
    for (int r = 0; r < CO_R; ++r)
        partial[(((size_t)s * 10 + b) * COUT + co_base + r) * SP + threadIdx.x] = acc[r];
}

// ---------------------------------------------------------------------------
// conv2/conv3 split-K (unchanged)
// ---------------------------------------------------------------------------
template<int CIN,int COUT,int HIN,int WIN,int CK,int CO_R,int COS>
__global__ __launch_bounds__(256) void conv_small_splitk(const float* __restrict__ in,
    const float* __restrict__ w, float* __restrict__ partial)
{
    constexpr int HOUT = HIN/2, WOUT = WIN/2;
    constexpr int SP = HOUT * WOUT;
    static_assert(SP * COS == 256, "block covers SP x COS");
    constexpr int HP = HIN + 1, WP = WIN + 2;
    __shared__ float sb[CK * HP * WP];
    const int b = blockIdx.y;
    const int s = blockIdx.z;
    const int sp_i = threadIdx.x % SP;
    const int slot = threadIdx.x / SP;
    const int co_base = (blockIdx.x * COS + slot) * CO_R;
    const int oy = sp_i / WOUT, ox = sp_i % WOUT;
    const int ci0 = s * CK;
    const float* inb = in + (size_t)b * CIN * HIN * WIN;

    for (int i = threadIdx.x; i < CK * HP * WP; i += 256) {
        int c = i % WP; int r = (i / WP) % HP; int cl = i / (WP * HP);
        float v = 0.f;
        if (r < HIN && c < WIN) v = inb[((size_t)(ci0 + cl) * HIN + r) * WIN + c];
        sb[i] = v;
    }
    __syncthreads();

    float acc[CO_R] = {};
    #pragma unroll
    for (int cl = 0; cl < CK; ++cl) {
        const float* sp = &sb[(cl * HP + 2 * oy) * WP + 2 * ox];
        float x[3][3];
        #pragma unroll
        for (int dy = 0; dy < 3; ++dy) {
            float2 f = *(const float2*)&sp[dy * WP];
            x[dy][0] = f.x; x[dy][1] = f.y; x[dy][2] = sp[dy * WP + 2];
        }
        const float* wp = w + ((size_t)co_base * CIN + (ci0 + cl)) * 9;
        #pragma unroll
        for (int r = 0; r < CO_R; ++r) {
            const float* wr = wp + (size_t)r * CIN * 9;
            #pragma unroll
            for (int dy = 0; dy < 3; ++dy)
                #pragma unroll
                for (int dx = 0; dx < 3; ++dx)
                    acc[r] = fmaf(wr[dy * 3 + dx], x[dy][dx], acc[r]);
        }
    }
    #pragma unroll
    for (int r = 0; r < CO_R; ++r)
        partial[(((size_t)s * 10 + b) * COUT + co_base + r) * SP + sp_i] = acc[r];
}

template<int COUT,int SP,int S>
__global__ void conv_reduce_relu(const float* __restrict__ partial, const float* __restrict__ bias,
                                 float* __restrict__ out, int total)
{
    int i = blockIdx.x * 256 + threadIdx.x;
    if (i >= total) return;
    int sp = i % SP; int co = (i / SP) % COUT; int b = i / (SP * COUT);
    float acc = bias[co];
    #pragma unroll
    for (int s = 0; s < S; ++s) acc += partial[(((size_t)s * 10 + b) * COUT + co) * SP + sp];
    out[i] = fmaxf(acc, 0.f);
}

// ---------------------------------------------------------------------------
// d0/d1 split-K quad (unchanged)
// ---------------------------------------------------------------------------
template<int CIN,int COUT,int HIN,int CK,int CO_R,int QPW>
__global__ __launch_bounds__(256) void deconv_quad_splitk(const float* __restrict__ in,
    const float* __restrict__ w, float* __restrict__ partial)
{
    constexpr int CPW = 64 / QPW;
    constexpr int HP2 = HIN + 2;
    constexpr int SP = 4 * HIN * HIN;
    constexpr int WOUT = 2 * HIN;
    static_assert(QPW == HIN * HIN, "wave quads cover input plane");
    __shared__ float sb[CK * HP2 * HP2];
    const int b = blockIdx.y, s = blockIdx.z;
    const int lane = threadIdx.x & 63;
    const int wv = threadIdx.x >> 6;
    const int q = lane % QPW;
    const int co_off = lane / QPW;
    const int t = q / HIN, u = q % HIN;
    const int co_base = (blockIdx.x * 4 + wv) * CPW * CO_R + co_off * CO_R;
    const int ci0 = s * CK;
    const float* inb = in + (size_t)b * CIN * HIN * HIN;

    for (int i = threadIdx.x; i < CK * HP2 * HP2; i += 256) {
        int c = i % HP2; int r = (i / HP2) % HP2; int cl = i / (HP2 * HP2);
        int gr = r - 1, gc = c - 1;
        float v = 0.f;
        if (gr >= 0 && gr < HIN && gc >= 0 && gc < HIN)
            v = inb[((size_t)(ci0 + cl) * HIN + gr) * HIN + gc];
        sb[i] = v;
    }
    __syncthreads();

    float acc[CO_R][4] = {};
    #pragma unroll 4
    for (int cl = 0; cl < CK; ++cl) {
        const float* sp = &sb[(cl * HP2 + t) * HP2 + u];
        float x00 = sp[0],       x01 = sp[1],       x02 = sp[2];
        float x10 = sp[HP2],     x11 = sp[HP2+1],   x12 = sp[HP2+2];
        float x20 = sp[2*HP2],   x21 = sp[2*HP2+1], x22 = sp[2*HP2+2];
        const float* wp = w + ((size_t)(ci0 + cl) * COUT + co_base) * 16;
        #pragma unroll
        for (int r = 0; r < CO_R; ++r) {
            const float* W_ = wp + r * 16;
            acc[r][0] += W_[5]*x11 + W_[7]*x10 + W_[13]*x01 + W_[15]*x00;
            acc[r][1] += W_[4]*x12 + W_[6]*x11 + W_[12]*x02 + W_[14]*x01;
            acc[r][2] += W_[1]*x21 + W_[3]*x20 + W_[9]*x11  + W_[11]*x10;
            acc[r][3] += W_[0]*x22 + W_[2]*x21 + W_[8]*x12  + W_[10]*x11;
        }
    }
    #pragma unroll
    for (int r = 0; r < CO_R; ++r) {
        float* pp = partial + (((size_t)s * 10 + b) * COUT + co_base + r) * SP;
        pp[(2*t)   * WOUT + 2*u]     = acc[r][0];
        pp[(2*t)   * WOUT + 2*u + 1] = acc[r][1];
        pp[(2*t+1) * WOUT + 2*u]     = acc[r][2];
        pp[(2*t+1) * WOUT + 2*u + 1] = acc[r][3];
    }
}

// ---------------------------------------------------------------------------
// d2/d3/d4 DIRECT: 4 waves/block, thread = one 2x2 quad x CO_R cos; 9 global
// loads per ci (L1/L2-served), wave-uniform scalar weights; no LDS/barriers.
// Lane map 4 rows x 16 cols: 16 contiguous lanes per input row (64B-aligned
// reads) and 128B-contiguous output row segments. co_base = (z*4+wave)*CO_R.
// ---------------------------------------------------------------------------
template<int CIN,int COUT,int HIN,int CO_R>
__global__ __launch_bounds__(256) void deconv_quad_direct(const float* __restrict__ in,
    const float* __restrict__ w, const float* __restrict__ bias, float* __restrict__ out)
{
    constexpr int WIN = HIN;
    constexpr int HOUT = 2 * HIN, WOUT = 2 * WIN;
    constexpr int TILES_W = WIN / 16;
    static_assert(WIN % 16 == 0 && HIN % 4 == 0, "4x16 quad tiles");

    const int lane = threadIdx.x & 63;
    const int wv   = __builtin_amdgcn_readfirstlane((int)(threadIdx.x >> 6));
    const int tile = blockIdx.x;
    const int tr = tile / TILES_W, tc = tile % TILES_W;
    const int b  = blockIdx.y;
    const int co_base = (blockIdx.z * 4 + wv) * CO_R;

    const int t = tr * 4 + (lane >> 4);
    const int u = tc * 16 + (lane & 15);
    const bool mr0 = t > 0, mr2 = t < HIN - 1, mc0 = u > 0, mc2 = u < WIN - 1;
    const int tm = mr0 ? t - 1 : t, tp = mr2 ? t + 1 : t;
    const int um = mc0 ? u - 1 : u, up = mc2 ? u + 1 : u;
    const int o00 = tm*WIN+um, o01 = tm*WIN+u, o02 = tm*WIN+up;
    const int o10 = t *WIN+um, o11 = t *WIN+u, o12 = t *WIN+up;
    const int o20 = tp*WIN+um, o21 = tp*WIN+u, o22 = tp*WIN+up;

    const float* p = in + (size_t)b * CIN * HIN * WIN;
    float acc[CO_R][4] = {};

    #pragma unroll 2
    for (int ci = 0; ci < CIN; ++ci) {
        float x00 = p[o00], x01 = p[o01], x02 = p[o02];
        float x10 = p[o10], x11 = p[o11], x12 = p[o12];
        float x20 = p[o20], x21 = p[o21], x22 = p[o22];
        x00 = (mr0 && mc0) ? x00 : 0.f;
        x01 = mr0 ? x01 : 0.f;
        x02 = (mr0 && mc2) ? x02 : 0.f;
        x10 = mc0 ? x10 : 0.f;
        x12 = mc2 ? x12 : 0.f;
        x20 = (mr2 && mc0) ? x20 : 0.f;
        x21 = mr2 ? x21 : 0.f;
        x22 = (mr2 && mc2) ? x22 : 0.f;

        const float* wp = w + ((size_t)ci * COUT + co_base) * 16;   // wave-uniform
        #pragma unroll
        for (int r = 0; r < CO_R; ++r) {
            const float* W_ = wp + r * 16;
            acc[r][0] += W_[5]*x11 + W_[7]*x10 + W_[13]*x01 + W_[15]*x00;
            acc[r][1] += W_[4]*x12 + W_[6]*x11 + W_[12]*x02 + W_[14]*x01;
            acc[r][2] += W_[1]*x21 + W_[3]*x20 + W_[9]*x11  + W_[11]*x10;
            acc[r][3] += W_[0]*x22 + W_[2]*x21 + W_[8]*x12  + W_[10]*x11;
        }
        p += HIN * WIN;
    }

    #pragma unroll
    for (int r = 0; r < CO_R; ++r) {
        int co = co_base + r;
        float bi = bias[co];
        float* ob = out + (((size_t)b * COUT + co) * HOUT + 2 * t) * WOUT + 2 * u;
        float2 v0, v1;
        v0.x = fmaxf(acc[r][0] + bi, 0.f);
        v0.y = fmaxf(acc[r][1] + bi, 0.f);
        v1.x = fmaxf(acc[r][2] + bi, 0.f);
        v1.y = fmaxf(acc[r][3] + bi, 0.f);
        *(float2*)ob = v0;
        *(float2*)&ob[WOUT] = v1;
    }
}

// ---------------------------------------------------------------------------
// Split-K FC (unchanged)
// ---------------------------------------------------------------------------
template<int KC>
__global__ __launch_bounds__(256) void fc_splitk(const float* __restrict__ in,
    const float* __restrict__ W, float* __restrict__ partial, int K, int N)
{
    __shared__ float s_in[10 * KC];
    const int o = blockIdx.x * 256 + threadIdx.x;
    const int k0 = blockIdx.y * KC;
    for (int i = threadIdx.x; i < 10 * KC; i += 256) {
        int b = i / KC, k = i % KC;
        s_in[i] = in[(size_t)b * K + k0 + k];
    }
    __syncthreads();

    float acc[10];
    #pragma unroll
    for (int b = 0; b < 10; ++b) acc[b] = 0.f;
    const float* wp = W + (size_t)k0 * N + o;
    #pragma unroll 4
    for (int k = 0; k < KC; ++k) {
        float wv = wp[(size_t)k * N];
        #pragma unroll
        for (int b = 0; b < 10; ++b) acc[b] = fmaf(wv, s_in[b * KC + k], acc[b]);
    }
    float* pp = partial + ((size_t)blockIdx.y * 10) * N + o;
    #pragma unroll
    for (int b = 0; b < 10; ++b) pp[(size_t)b * N] = acc[b];
}

__global__ void fc_reduce_relu(const float* __restrict__ partial, const float* __restrict__ bias,
                               float* __restrict__ out, int N, int S)
{
    int i = blockIdx.x * 256 + threadIdx.x;
    if (i >= 10 * N) return;
    int o = i % N, b = i / N;
    float acc = bias[o];
    for (int s = 0; s < S; ++s) acc += partial[((size_t)s * 10 + b) * N + o];
    out[(size_t)b * N + o] = fmaxf(acc, 0.f);
}

// ---------------------------------------------------------------------------
// Final fused: 1x1 convs + geometry (unchanged)
// ---------------------------------------------------------------------------
__global__ __launch_bounds__(256) void final_fused_v2(const float* __restrict__ h,
    const float* __restrict__ xyzw, const float* __restrict__ xyzb,
    const float* __restrict__ maskw, const float* __restrict__ maskb,
    const float* __restrict__ quat, float* __restrict__ out)
{
    const int V = 8, HW = 128 * 128, C = 48, Bn = 10, VHW = V * HW;
    __shared__ float4 sh[48 * 32];
    int b = blockIdx.y, tile = blockIdx.x;
    const float4* hb = (const float4*)h;
    for (int i = threadIdx.x; i < C * 32; i += 256) {
        int ci = i >> 5, p = i & 31;
        sh[i] = hb[(size_t)(b * C + ci) * (HW / 4) + tile * 32 + p];
    }
    __syncthreads();

    int pl = threadIdx.x & 31, v = threadIdx.x >> 5;
    float4 xr = {0,0,0,0}, yr = {0,0,0,0}, zr = {0,0,0,0}, mm = {0,0,0,0};
    const float* wx = xyzw + (size_t)(v * 3 + 0) * C;
    const float* wy = xyzw + (size_t)(v * 3 + 1) * C;
    const float* wz = xyzw + (size_t)(v * 3 + 2) * C;
    const float* wm = maskw + (size_t)v * C;
    for (int ci = 0; ci < C; ++ci) {
        float4 hv = sh[ci * 32 + pl];
        float a;
        a = wx[ci]; xr.x += a*hv.x; xr.y += a*hv.y; xr.z += a*hv.z; xr.w += a*hv.w;
        a = wy[ci]; yr.x += a*hv.x; yr.y += a*hv.y; yr.z += a*hv.z; yr.w += a*hv.w;
        a = wz[ci]; zr.x += a*hv.x; zr.y += a*hv.y; zr.z += a*hv.z; zr.w += a*hv.w;
        a = wm[ci]; mm.x += a*hv.x; mm.y += a*hv.y; mm.z += a*hv.z; mm.w += a*hv.w;
    }
    float bxv = xyzb[v * 3 + 0], byv = xyzb[v * 3 + 1], bzv = xyzb[v * 3 + 2], bmv = maskb[v];

    float qw = quat[v*4+0], qx = quat[v*4+1], qy = quat[v*4+2], qz = quat[v*4+3];
    float R00 = 1.f - 2.f*(qy*qy + qz*qz), R01 = 2.f*(qx*qy - qw*qz), R02 = 2.f*(qx*qz + qw*qy);
    float R10 = 2.f*(qx*qy + qw*qz), R11 = 1.f - 2.f*(qx*qx + qz*qz), R12 = 2.f*(qy*qz - qw*qx);
    float R20 = 2.f*(qx*qz - qw*qy), R21 = 2.f*(qy*qz + qw*qx), R22 = 1.f - 2.f*(qx*qx + qy*qy);

    float4 o0, o1, o2, om;
    float* X = (float*)&xr; float* Y = (float*)&yr; float* Z = (float*)&zr; float* M = (float*)&mm;
    float* O0 = (float*)&o0; float* O1 = (float*)&o1; float* O2 = (float*)&o2; float* OM = (float*)&om;
    #pragma unroll
    for (int j = 0; j < 4; ++j) {
        float camX = (X[j] + bxv) * (1.f / 64.f) - 0.5f;
        float camY = -(Y[j] + byv) * (1.f / 64.f) + 0.5f;
        float camZ = -((Z[j] + bzv) + 1.0f);
        O0[j] = R00 * camX + R10 * camY + R20 * camZ;
        O1[j] = R01 * camX + R11 * camY + R21 * camZ;
        O2[j] = R02 * camX + R12 * camY + R22 * camZ;
        OM[j] = M[j] + bmv;
    }

    size_t o = (size_t)v * HW + tile * 128 + pl * 4;
    float4* op = (float4*)out;
    op[((size_t)(b * 3 + 0) * VHW + o) >> 2] = o0;
    op[((size_t)(b * 3 + 1) * VHW + o) >> 2] = o1;
    op[((size_t)(b * 3 + 2) * VHW + o) >> 2] = o2;
    op[((size_t)Bn * 3 * VHW + (size_t)b * VHW + o) >> 2] = om;
}

// ---------------------------------------------------------------------------

extern "C" void kernel_launch(void* const* d_in, const int* in_sizes, int n_in,
                              void* d_out, int out_size, void* d_ws, size_t ws_size,
                              hipStream_t stream)
{
    const float* x    = (const float*)d_in[0];
    const float* ew0  = (const float*)d_in[1];
    const float* eb0  = (const float*)d_in[2];
    const float* ew1  = (const float*)d_in[3];
    const float* eb1  = (const float*)d_in[4];
    const float* ew2  = (const float*)d_in[5];
    const float* eb2  = (const float*)d_in[6];
    const float* ew3  = (const float*)d_in[7];
    const float* eb3  = (const float*)d_in[8];
    const float* efw  = (const float*)d_in[9];
    const float* efb  = (const float*)d_in[10];
    const float* dfw  = (const float*)d_in[11];
    const float* dfb  = (const float*)d_in[12];
    const float* dw0  = (const float*)d_in[13];
    const float* db0  = (const float*)d_in[14];
    const float* dw1  = (const float*)d_in[15];
    const float* db1  = (const float*)d_in[16];
    const float* dw2  = (const float*)d_in[17];
    const float* db2  = (const float*)d_in[18];
    const float* dw3  = (const float*)d_in[19];
    const float* db3  = (const float*)d_in[20];
    const float* dw4  = (const float*)d_in[21];
    const float* db4  = (const float*)d_in[22];
    const float* xyzw = (const float*)d_in[23];
    const float* xyzb = (const float*)d_in[24];
    const float* maskw= (const float*)d_in[25];
    const float* maskb= (const float*)d_in[26];
    const float* quat = (const float*)d_in[27];
    float* out = (float*)d_out;

    float* A   = (float*)d_ws;
    float* Bb  = A + 7864320;
    float* P1  = A;                 // fc1 partials 128*10*512 = 655,360
    float* L   = A + 1000000;       // latent 5120
    float* P2  = Bb + 1000000;      // fc2 partials 16*10*4096 = 655,360
    float* H0  = Bb;                // fc2 out 40,960
    float* PC1 = A + 2000000;       // conv1 partials 2,621,440
    float* PC2 = A + 2000000;       // conv2 partials 983,040
    float* PC3 = Bb + 500000;       // conv3 partials 491,520
    float* PD0 = A + 2000000;       // d0 partials 491,520
    float* PD1 = Bb + 1000000;      // d1 partials 1,310,720

    const int TB = 256;

    // encoder
    conv3x3_c3<<<3840, 256, 0, stream>>>(x, ew0, eb0, A);
    conv_splitk_big<96,128,32,32,8,6,16><<<dim3(8,10,8), 256, 0, stream>>>(A, ew1, PC1);
    conv_reduce_relu<128,256,8><<<CDIV(327680,TB), TB, 0, stream>>>(PC1, eb1, Bb, 327680);
    conv_small_splitk<128,192,16,16,16,3,4><<<dim3(16,10,8), 256, 0, stream>>>(Bb, ew2, PC2);
    conv_reduce_relu<192,64,8><<<CDIV(122880,TB), TB, 0, stream>>>(PC2, eb2, A, 122880);
    conv_small_splitk<192,256,8,8,16,1,16><<<dim3(16,10,12), 256, 0, stream>>>(A, ew3, PC3);
    conv_reduce_relu<256,16,12><<<CDIV(40960,TB), TB, 0, stream>>>(PC3, eb3, Bb, 40960);

    // fc
    fc_splitk<32><<<dim3(2, 128), 256, 0, stream>>>(Bb, efw, P1, 4096, 512);
    fc_reduce_relu<<<CDIV(10 * 512, TB), TB, 0, stream>>>(P1, efb, L, 512, 128);
    fc_splitk<32><<<dim3(16, 16), 256, 0, stream>>>(L, dfw, P2, 512, 4096);
    fc_reduce_relu<<<CDIV(10 * 4096, TB), TB, 0, stream>>>(P2, dfb, H0, 4096, 16);

    // decoder
    deconv_quad_splitk<256,192,4,64,1,16><<<dim3(12,10,4), 256, 0, stream>>>(H0, dw0, PD0);
    conv_reduce_relu<192,64,4><<<CDIV(122880,TB), TB, 0, stream>>>(PD0, db0, A, 122880);
    deconv_quad_splitk<192,128,8,48,2,64><<<dim3(16,10,4), 256, 0, stream>>>(A, dw1, PD1);
    conv_reduce_relu<128,256,4><<<CDIV(327680,TB), TB, 0, stream>>>(PD1, db1, Bb, 327680);

    // d2: 4 tiles x 12 co-slices = 480 blocks (4x16 lane map: tiles = (16/4)*(16/16) = 4)
    deconv_quad_direct<128, 96, 16, 2><<<dim3( 4, 10, 12), 256, 0, stream>>>(Bb, dw2, db2, A);
    // d3: 16 tiles x 8 co-slices = 1280 blocks ((32/4)*(32/16) = 16)
    deconv_quad_direct< 96, 64, 32, 2><<<dim3(16, 10,  8), 256, 0, stream>>>(A,  dw3, db3, Bb);
    // d4: 64 tiles x 2 co-halves = 1280 blocks = 5/CU exact ((64/4)*(64/16) = 64), CO_R=6
    deconv_quad_direct< 64, 48, 64, 6><<<dim3(64, 10,  2), 256, 0, stream>>>(Bb, dw4, db4, A);

    // fused 1x1 convs + geometry -> d_out
    final_fused_v2<<<dim3(128, 10), 256, 0, stream>>>(A, xyzw, xyzb, maskw, maskb, quat, out);
}

// Round 12
// 428.211 us; speedup vs baseline: 1.0343x; 1.0343x over previous
//
#include <hip/hip_runtime.h>

#define CDIV(a,b) (((a)+(b)-1)/(b))

// ---------------------------------------------------------------------------
// conv0: 3->96, 64x64 -> 32x32, fully unrolled
// ---------------------------------------------------------------------------
__global__ __launch_bounds__(256) void conv3x3_c3(const float* __restrict__ in,
    const float* __restrict__ w, const float* __restrict__ bias, float* __restrict__ out)
{
    int idx = blockIdx.x * 256 + threadIdx.x;     // 10*96*32*32 = 983040 exact
    int ox = idx & 31; int t = idx >> 5;
    int oy = t & 31;   t >>= 5;
    int co = t % 96;   int b = t / 96;
    float acc = bias[co];
    const float* wp  = w + co * 27;
    const float* ipb = in + (size_t)b * 3 * 64 * 64;
    #pragma unroll
    for (int ci = 0; ci < 3; ++ci) {
        #pragma unroll
        for (int ky = 0; ky < 3; ++ky) {
            int iy = 2 * oy + ky;
            #pragma unroll
            for (int kx = 0; kx < 3; ++kx) {
                int ix = 2 * ox + kx;
                if (iy < 64 && ix < 64)
                    acc = fmaf(wp[ci * 9 + ky * 3 + kx], ipb[(ci * 64 + iy) * 64 + ix], acc);
            }
        }
    }
    out[idx] = fmaxf(acc, 0.f);
}

// ---------------------------------------------------------------------------
// conv1: ci-split-K with LDS staging
// ---------------------------------------------------------------------------
template<int CIN,int COUT,int HIN,int WIN,int SPLITS,int CK,int CO_R>
__global__ __launch_bounds__(256) void conv_splitk_big(const float* __restrict__ in,
    const float* __restrict__ w, float* __restrict__ partial)
{
    constexpr int HOUT = HIN/2, WOUT = WIN/2;
    constexpr int SP = HOUT * WOUT;
    static_assert(SP == 256, "one output px per thread");
    constexpr int HP = HIN + 1, WP = WIN + 2;
    constexpr int CSL = CIN / SPLITS;
    constexpr int NCH = CSL / CK;
    static_assert(CSL % CK == 0, "CK must divide ci slice");
    constexpr int SELEM = CK * HP * WP;
    constexpr int NLD = (SELEM + 255) / 256;
    __shared__ float sb[SELEM];

    const int b = blockIdx.y, s = blockIdx.z;
    const int co_base = blockIdx.x * CO_R;
    const int oy = threadIdx.x >> 4, ox = threadIdx.x & 15;
    const int ci00 = s * CSL;
    const float* inb = in + (size_t)b * CIN * HIN * WIN;

    float rg[NLD];
    auto load_chunk = [&](int ci0) {
        #pragma unroll
        for (int j = 0; j < NLD; ++j) {
            int i = threadIdx.x + j * 256;
            float v = 0.f;
            if (i < SELEM) {
                int c = i % WP; int r = (i / WP) % HP; int cl = i / (WP * HP);
                if (r < HIN && c < WIN) v = inb[((size_t)(ci0 + cl) * HIN + r) * WIN + c];
            }
            rg[j] = v;
        }
    };
    load_chunk(ci00);

    float acc[CO_R] = {};
    for (int ch = 0; ch < NCH; ++ch) {
        #pragma unroll
        for (int j = 0; j < NLD; ++j) {
            int i = threadIdx.x + j * 256;
            if (i < SELEM) sb[i] = rg[j];
        }
        __syncthreads();
        if (ch + 1 < NCH) load_chunk(ci00 + (ch + 1) * CK);

        #pragma unroll
        for (int cl = 0; cl < CK; ++cl) {
            const float* sp = &sb[(cl * HP + 2 * oy) * WP + 2 * ox];
            float x[3][3];
            #pragma unroll
            for (int dy = 0; dy < 3; ++dy) {
                float2 f = *(const float2*)&sp[dy * WP];
                x[dy][0] = f.x; x[dy][1] = f.y; x[dy][2] = sp[dy * WP + 2];
            }
            int ci = ci00 + ch * CK + cl;
            const float* wp = w + ((size_t)co_base * CIN + ci) * 9;
            #pragma unroll
            for (int r = 0; r < CO_R; ++r) {
                const float* wr = wp + (size_t)r * CIN * 9;
                #pragma unroll
                for (int dy = 0; dy < 3; ++dy)
                    #pragma unroll
                    for (int dx = 0; dx < 3; ++dx)
                        acc[r] = fmaf(wr[dy * 3 + dx], x[dy][dx], acc[r]);
            }
        }
        __syncthreads();
    }
    #pragma unroll
    for (int r = 0; r < CO_R; ++r)
        partial[(((size_t)s * 10 + b) * COUT + co_base + r) * SP + threadIdx.x] = acc[r];
}

// ---------------------------------------------------------------------------
// conv2/conv3 split-K (unchanged)
// ---------------------------------------------------------------------------
template<int CIN,int COUT,int HIN,int WIN,int CK,int CO_R,int COS>
__global__ __launch_bounds__(256) void conv_small_splitk(const float* __restrict__ in,
    const float* __restrict__ w, float* __restrict__ partial)
{
    constexpr int HOUT = HIN/2, WOUT = WIN/2;
    constexpr int SP = HOUT * WOUT;
    static_assert(SP * COS == 256, "block covers SP x COS");
    constexpr int HP = HIN + 1, WP = WIN + 2;
    __shared__ float sb[CK * HP * WP];
    const int b = blockIdx.y;
    const int s = blockIdx.z;
    const int sp_i = threadIdx.x % SP;
    const int slot = threadIdx.x / SP;
    const int co_base = (blockIdx.x * COS + slot) * CO_R;
    const int oy = sp_i / WOUT, ox = sp_i % WOUT;
    const int ci0 = s * CK;
    const float* inb = in + (size_t)b * CIN * HIN * WIN;

    for (int i = threadIdx.x; i < CK * HP * WP; i += 256) {
        int c = i % WP; int r = (i / WP) % HP; int cl = i / (WP * HP);
        float v = 0.f;
        if (r < HIN && c < WIN) v = inb[((size_t)(ci0 + cl) * HIN + r) * WIN + c];
        sb[i] = v;
    }
    __syncthreads();

    float acc[CO_R] = {};
    #pragma unroll
    for (int cl = 0; cl < CK; ++cl) {
        const float* sp = &sb[(cl * HP + 2 * oy) * WP + 2 * ox];
        float x[3][3];
        #pragma unroll
        for (int dy = 0; dy < 3; ++dy) {
            float2 f = *(const float2*)&sp[dy * WP];
            x[dy][0] = f.x; x[dy][1] = f.y; x[dy][2] = sp[dy * WP + 2];
        }
        const float* wp = w + ((size_t)co_base * CIN + (ci0 + cl)) * 9;
        #pragma unroll
        for (int r = 0; r < CO_R; ++r) {
            const float* wr = wp + (size_t)r * CIN * 9;
            #pragma unroll
            for (int dy = 0; dy < 3; ++dy)
                #pragma unroll
                for (int dx = 0; dx < 3; ++dx)
                    acc[r] = fmaf(wr[dy * 3 + dx], x[dy][dx], acc[r]);
        }
    }
    #pragma unroll
    for (int r = 0; r < CO_R; ++r)
        partial[(((size_t)s * 10 + b) * COUT + co_base + r) * SP + sp_i] = acc[r];
}

template<int COUT,int SP,int S>
__global__ void conv_reduce_relu(const float* __restrict__ partial, const float* __restrict__ bias,
                                 float* __restrict__ out, int total)
{
    int i = blockIdx.x * 256 + threadIdx.x;
    if (i >= total) return;
    int sp = i % SP; int co = (i / SP) % COUT; int b = i / (SP * COUT);
    float acc = bias[co];
    #pragma unroll
    for (int s = 0; s < S; ++s) acc += partial[(((size_t)s * 10 + b) * COUT + co) * SP + sp];
    out[i] = fmaxf(acc, 0.f);
}

// ---------------------------------------------------------------------------
// d0/d1 split-K quad (unchanged)
// ---------------------------------------------------------------------------
template<int CIN,int COUT,int HIN,int CK,int CO_R,int QPW>
__global__ __launch_bounds__(256) void deconv_quad_splitk(const float* __restrict__ in,
    const float* __restrict__ w, float* __restrict__ partial)
{
    constexpr int CPW = 64 / QPW;
    constexpr int HP2 = HIN + 2;
    constexpr int SP = 4 * HIN * HIN;
    constexpr int WOUT = 2 * HIN;
    static_assert(QPW == HIN * HIN, "wave quads cover input plane");
    __shared__ float sb[CK * HP2 * HP2];
    const int b = blockIdx.y, s = blockIdx.z;
    const int lane = threadIdx.x & 63;
    const int wv = threadIdx.x >> 6;
    const int q = lane % QPW;
    const int co_off = lane / QPW;
    const int t = q / HIN, u = q % HIN;
    const int co_base = (blockIdx.x * 4 + wv) * CPW * CO_R + co_off * CO_R;
    const int ci0 = s * CK;
    const float* inb = in + (size_t)b * CIN * HIN * HIN;

    for (int i = threadIdx.x; i < CK * HP2 * HP2; i += 256) {
        int c = i % HP2; int r = (i / HP2) % HP2; int cl = i / (HP2 * HP2);
        int gr = r - 1, gc = c - 1;
        float v = 0.f;
        if (gr >= 0 && gr < HIN && gc >= 0 && gc < HIN)
            v = inb[((size_t)(ci0 + cl) * HIN + gr) * HIN + gc];
        sb[i] = v;
    }
    __syncthreads();

    float acc[CO_R][4] = {};
    #pragma unroll 4
    for (int cl = 0; cl < CK; ++cl) {
        const float* sp = &sb[(cl * HP2 + t) * HP2 + u];
        float x00 = sp[0],       x01 = sp[1],       x02 = sp[2];
        float x10 = sp[HP2],     x11 = sp[HP2+1],   x12 = sp[HP2+2];
        float x20 = sp[2*HP2],   x21 = sp[2*HP2+1], x22 = sp[2*HP2+2];
        const float* wp = w + ((size_t)(ci0 + cl) * COUT + co_base) * 16;
        #pragma unroll
        for (int r = 0; r < CO_R; ++r) {
            const float* W_ = wp + r * 16;
            acc[r][0] += W_[5]*x11 + W_[7]*x10 + W_[13]*x01 + W_[15]*x00;
            acc[r][1] += W_[4]*x12 + W_[6]*x11 + W_[12]*x02 + W_[14]*x01;
            acc[r][2] += W_[1]*x21 + W_[3]*x20 + W_[9]*x11  + W_[11]*x10;
            acc[r][3] += W_[0]*x22 + W_[2]*x21 + W_[8]*x12  + W_[10]*x11;
        }
    }
    #pragma unroll
    for (int r = 0; r < CO_R; ++r) {
        float* pp = partial + (((size_t)s * 10 + b) * COUT + co_base + r) * SP;
        pp[(2*t)   * WOUT + 2*u]     = acc[r][0];
        pp[(2*t)   * WOUT + 2*u + 1] = acc[r][1];
        pp[(2*t+1) * WOUT + 2*u]     = acc[r][2];
        pp[(2*t+1) * WOUT + 2*u + 1] = acc[r][3];
    }
}

// ---------------------------------------------------------------------------
// d2/d3/d4 DIRECT: 4 waves/block, thread = one 2x2 quad x CO_R cos; 9 global
// loads per ci (L1/L2-served), wave-uniform scalar weights; no LDS/barriers.
// Lane map 4 rows x 16 cols (64B-aligned reads, 128B output segments).
// ---------------------------------------------------------------------------
template<int CIN,int COUT,int HIN,int CO_R>
__global__ __launch_bounds__(256) void deconv_quad_direct(const float* __restrict__ in,
    const float* __restrict__ w, const float* __restrict__ bias, float* __restrict__ out)
{
    constexpr int WIN = HIN;
    constexpr int HOUT = 2 * HIN, WOUT = 2 * WIN;
    constexpr int TILES_W = WIN / 16;
    static_assert(WIN % 16 == 0 && HIN % 4 == 0, "4x16 quad tiles");

    const int lane = threadIdx.x & 63;
    const int wv   = __builtin_amdgcn_readfirstlane((int)(threadIdx.x >> 6));
    const int tile = blockIdx.x;
    const int tr = tile / TILES_W, tc = tile % TILES_W;
    const int b  = blockIdx.y;
    const int co_base = (blockIdx.z * 4 + wv) * CO_R;

    const int t = tr * 4 + (lane >> 4);
    const int u = tc * 16 + (lane & 15);
    const bool mr0 = t > 0, mr2 = t < HIN - 1, mc0 = u > 0, mc2 = u < WIN - 1;
    const int tm = mr0 ? t - 1 : t, tp = mr2 ? t + 1 : t;
    const int um = mc0 ? u - 1 : u, up = mc2 ? u + 1 : u;
    const int o00 = tm*WIN+um, o01 = tm*WIN+u, o02 = tm*WIN+up;
    const int o10 = t *WIN+um, o11 = t *WIN+u, o12 = t *WIN+up;
    const int o20 = tp*WIN+um, o21 = tp*WIN+u, o22 = tp*WIN+up;

    const float* p = in + (size_t)b * CIN * HIN * WIN;
    float acc[CO_R][4] = {};

    #pragma unroll 2
    for (int ci = 0; ci < CIN; ++ci) {
        float x00 = p[o00], x01 = p[o01], x02 = p[o02];
        float x10 = p[o10], x11 = p[o11], x12 = p[o12];
        float x20 = p[o20], x21 = p[o21], x22 = p[o22];
        x00 = (mr0 && mc0) ? x00 : 0.f;
        x01 = mr0 ? x01 : 0.f;
        x02 = (mr0 && mc2) ? x02 : 0.f;
        x10 = mc0 ? x10 : 0.f;
        x12 = mc2 ? x12 : 0.f;
        x20 = (mr2 && mc0) ? x20 : 0.f;
        x21 = mr2 ? x21 : 0.f;
        x22 = (mr2 && mc2) ? x22 : 0.f;

        const float* wp = w + ((size_t)ci * COUT + co_base) * 16;   // wave-uniform
        #pragma unroll
        for (int r = 0; r < CO_R; ++r) {
            const float* W_ = wp + r * 16;
            acc[r][0] += W_[5]*x11 + W_[7]*x10 + W_[13]*x01 + W_[15]*x00;
            acc[r][1] += W_[4]*x12 + W_[6]*x11 + W_[12]*x02 + W_[14]*x01;
            acc[r][2] += W_[1]*x21 + W_[3]*x20 + W_[9]*x11  + W_[11]*x10;
            acc[r][3] += W_[0]*x22 + W_[2]*x21 + W_[8]*x12  + W_[10]*x11;
        }
        p += HIN * WIN;
    }

    #pragma unroll
    for (int r = 0; r < CO_R; ++r) {
        int co = co_base + r;
        float bi = bias[co];
        float* ob = out + (((size_t)b * COUT + co) * HOUT + 2 * t) * WOUT + 2 * u;
        float2 v0, v1;
        v0.x = fmaxf(acc[r][0] + bi, 0.f);
        v0.y = fmaxf(acc[r][1] + bi, 0.f);
        v1.x = fmaxf(acc[r][2] + bi, 0.f);
        v1.y = fmaxf(acc[r][3] + bi, 0.f);
        *(float2*)ob = v0;
        *(float2*)&ob[WOUT] = v1;
    }
}

// ---------------------------------------------------------------------------
// Split-K FC (unchanged)
// ---------------------------------------------------------------------------
template<int KC>
__global__ __launch_bounds__(256) void fc_splitk(const float* __restrict__ in,
    const float* __restrict__ W, float* __restrict__ partial, int K, int N)
{
    __shared__ float s_in[10 * KC];
    const int o = blockIdx.x * 256 + threadIdx.x;
    const int k0 = blockIdx.y * KC;
    for (int i = threadIdx.x; i < 10 * KC; i += 256) {
        int b = i / KC, k = i % KC;
        s_in[i] = in[(size_t)b * K + k0 + k];
    }
    __syncthreads();

    float acc[10];
    #pragma unroll
    for (int b = 0; b < 10; ++b) acc[b] = 0.f;
    const float* wp = W + (size_t)k0 * N + o;
    #pragma unroll 4
    for (int k = 0; k < KC; ++k) {
        float wv = wp[(size_t)k * N];
        #pragma unroll
        for (int b = 0; b < 10; ++b) acc[b] = fmaf(wv, s_in[b * KC + k], acc[b]);
    }
    float* pp = partial + ((size_t)blockIdx.y * 10) * N + o;
    #pragma unroll
    for (int b = 0; b < 10; ++b) pp[(size_t)b * N] = acc[b];
}

__global__ void fc_reduce_relu(const float* __restrict__ partial, const float* __restrict__ bias,
                               float* __restrict__ out, int N, int S)
{
    int i = blockIdx.x * 256 + threadIdx.x;
    if (i >= 10 * N) return;
    int o = i % N, b = i / N;
    float acc = bias[o];
    for (int s = 0; s < S; ++s) acc += partial[((size_t)s * 10 + b) * N + o];
    out[(size_t)b * N + o] = fmaxf(acc, 0.f);
}

// ---------------------------------------------------------------------------
// Final fused: 1x1 convs + geometry (unchanged)
// ---------------------------------------------------------------------------
__global__ __launch_bounds__(256) void final_fused_v2(const float* __restrict__ h,
    const float* __restrict__ xyzw, const float* __restrict__ xyzb,
    const float* __restrict__ maskw, const float* __restrict__ maskb,
    const float* __restrict__ quat, float* __restrict__ out)
{
    const int V = 8, HW = 128 * 128, C = 48, Bn = 10, VHW = V * HW;
    __shared__ float4 sh[48 * 32];
    int b = blockIdx.y, tile = blockIdx.x;
    const float4* hb = (const float4*)h;
    for (int i = threadIdx.x; i < C * 32; i += 256) {
        int ci = i >> 5, p = i & 31;
        sh[i] = hb[(size_t)(b * C + ci) * (HW / 4) + tile * 32 + p];
    }
    __syncthreads();

    int pl = threadIdx.x & 31, v = threadIdx.x >> 5;
    float4 xr = {0,0,0,0}, yr = {0,0,0,0}, zr = {0,0,0,0}, mm = {0,0,0,0};
    const float* wx = xyzw + (size_t)(v * 3 + 0) * C;
    const float* wy = xyzw + (size_t)(v * 3 + 1) * C;
    const float* wz = xyzw + (size_t)(v * 3 + 2) * C;
    const float* wm = maskw + (size_t)v * C;
    for (int ci = 0; ci < C; ++ci) {
        float4 hv = sh[ci * 32 + pl];
        float a;
        a = wx[ci]; xr.x += a*hv.x; xr.y += a*hv.y; xr.z += a*hv.z; xr.w += a*hv.w;
        a = wy[ci]; yr.x += a*hv.x; yr.y += a*hv.y; yr.z += a*hv.z; yr.w += a*hv.w;
        a = wz[ci]; zr.x += a*hv.x; zr.y += a*hv.y; zr.z += a*hv.z; zr.w += a*hv.w;
        a = wm[ci]; mm.x += a*hv.x; mm.y += a*hv.y; mm.z += a*hv.z; mm.w += a*hv.w;
    }
    float bxv = xyzb[v * 3 + 0], byv = xyzb[v * 3 + 1], bzv = xyzb[v * 3 + 2], bmv = maskb[v];

    float qw = quat[v*4+0], qx = quat[v*4+1], qy = quat[v*4+2], qz = quat[v*4+3];
    float R00 = 1.f - 2.f*(qy*qy + qz*qz), R01 = 2.f*(qx*qy - qw*qz), R02 = 2.f*(qx*qz + qw*qy);
    float R10 = 2.f*(qx*qy + qw*qz), R11 = 1.f - 2.f*(qx*qx + qz*qz), R12 = 2.f*(qy*qz - qw*qx);
    float R20 = 2.f*(qx*qz - qw*qy), R21 = 2.f*(qy*qz + qw*qx), R22 = 1.f - 2.f*(qx*qx + qy*qy);

    float4 o0, o1, o2, om;
    float* X = (float*)&xr; float* Y = (float*)&yr; float* Z = (float*)&zr; float* M = (float*)&mm;
    float* O0 = (float*)&o0; float* O1 = (float*)&o1; float* O2 = (float*)&o2; float* OM = (float*)&om;
    #pragma unroll
    for (int j = 0; j < 4; ++j) {
        float camX = (X[j] + bxv) * (1.f / 64.f) - 0.5f;
        float camY = -(Y[j] + byv) * (1.f / 64.f) + 0.5f;
        float camZ = -((Z[j] + bzv) + 1.0f);
        O0[j] = R00 * camX + R10 * camY + R20 * camZ;
        O1[j] = R01 * camX + R11 * camY + R21 * camZ;
        O2[j] = R02 * camX + R12 * camY + R22 * camZ;
        OM[j] = M[j] + bmv;
    }

    size_t o = (size_t)v * HW + tile * 128 + pl * 4;
    float4* op = (float4*)out;
    op[((size_t)(b * 3 + 0) * VHW + o) >> 2] = o0;
    op[((size_t)(b * 3 + 1) * VHW + o) >> 2] = o1;
    op[((size_t)(b * 3 + 2) * VHW + o) >> 2] = o2;
    op[((size_t)Bn * 3 * VHW + (size_t)b * VHW + o) >> 2] = om;
}

// ---------------------------------------------------------------------------

extern "C" void kernel_launch(void* const* d_in, const int* in_sizes, int n_in,
                              void* d_out, int out_size, void* d_ws, size_t ws_size,
                              hipStream_t stream)
{
    const float* x    = (const float*)d_in[0];
    const float* ew0  = (const float*)d_in[1];
    const float* eb0  = (const float*)d_in[2];
    const float* ew1  = (const float*)d_in[3];
    const float* eb1  = (const float*)d_in[4];
    const float* ew2  = (const float*)d_in[5];
    const float* eb2  = (const float*)d_in[6];
    const float* ew3  = (const float*)d_in[7];
    const float* eb3  = (const float*)d_in[8];
    const float* efw  = (const float*)d_in[9];
    const float* efb  = (const float*)d_in[10];
    const float* dfw  = (const float*)d_in[11];
    const float* dfb  = (const float*)d_in[12];
    const float* dw0  = (const float*)d_in[13];
    const float* db0  = (const float*)d_in[14];
    const float* dw1  = (const float*)d_in[15];
    const float* db1  = (const float*)d_in[16];
    const float* dw2  = (const float*)d_in[17];
    const float* db2  = (const float*)d_in[18];
    const float* dw3  = (const float*)d_in[19];
    const float* db3  = (const float*)d_in[20];
    const float* dw4  = (const float*)d_in[21];
    const float* db4  = (const float*)d_in[22];
    const float* xyzw = (const float*)d_in[23];
    const float* xyzb = (const float*)d_in[24];
    const float* maskw= (const float*)d_in[25];
    const float* maskb= (const float*)d_in[26];
    const float* quat = (const float*)d_in[27];
    float* out = (float*)d_out;

    float* A   = (float*)d_ws;
    float* Bb  = A + 7864320;
    float* P1  = A;                 // fc1 partials 128*10*512 = 655,360
    float* L   = A + 1000000;       // latent 5120
    float* P2  = Bb + 1000000;      // fc2 partials 16*10*4096 = 655,360
    float* H0  = Bb;                // fc2 out 40,960
    float* PC1 = A + 2000000;       // conv1 partials 16*10*128*256 = 5,242,880 (ends 7.24M < 7.86M)
    float* PC2 = A + 2000000;       // conv2 partials 983,040
    float* PC3 = Bb + 500000;       // conv3 partials 491,520
    float* PD0 = A + 2000000;       // d0 partials 491,520
    float* PD1 = Bb + 1000000;      // d1 partials 1,310,720

    const int TB = 256;

    // encoder
    conv3x3_c3<<<3840, 256, 0, stream>>>(x, ew0, eb0, A);
    // conv1: SPLITS=16, single 6-ci chunk per block, 1280 blocks
    conv_splitk_big<96,128,32,32,16,6,16><<<dim3(8,10,16), 256, 0, stream>>>(A, ew1, PC1);
    conv_reduce_relu<128,256,16><<<CDIV(327680,TB), TB, 0, stream>>>(PC1, eb1, Bb, 327680);
    conv_small_splitk<128,192,16,16,16,3,4><<<dim3(16,10,8), 256, 0, stream>>>(Bb, ew2, PC2);
    conv_reduce_relu<192,64,8><<<CDIV(122880,TB), TB, 0, stream>>>(PC2, eb2, A, 122880);
    conv_small_splitk<192,256,8,8,16,1,16><<<dim3(16,10,12), 256, 0, stream>>>(A, ew3, PC3);
    conv_reduce_relu<256,16,12><<<CDIV(40960,TB), TB, 0, stream>>>(PC3, eb3, Bb, 40960);

    // fc
    fc_splitk<32><<<dim3(2, 128), 256, 0, stream>>>(Bb, efw, P1, 4096, 512);
    fc_reduce_relu<<<CDIV(10 * 512, TB), TB, 0, stream>>>(P1, efb, L, 512, 128);
    fc_splitk<32><<<dim3(16, 16), 256, 0, stream>>>(L, dfw, P2, 512, 4096);
    fc_reduce_relu<<<CDIV(10 * 4096, TB), TB, 0, stream>>>(P2, dfb, H0, 4096, 16);

    // decoder
    deconv_quad_splitk<256,192,4,64,1,16><<<dim3(12,10,4), 256, 0, stream>>>(H0, dw0, PD0);
    conv_reduce_relu<192,64,4><<<CDIV(122880,TB), TB, 0, stream>>>(PD0, db0, A, 122880);
    deconv_quad_splitk<192,128,8,48,2,64><<<dim3(16,10,4), 256, 0, stream>>>(A, dw1, PD1);
    conv_reduce_relu<128,256,4><<<CDIV(327680,TB), TB, 0, stream>>>(PD1, db1, Bb, 327680);

    // d2: 4 tiles x 12 co-slices = 480 blocks
    deconv_quad_direct<128, 96, 16, 2><<<dim3( 4, 10, 12), 256, 0, stream>>>(Bb, dw2, db2, A);
    // d3: 16 tiles x 8 co-slices = 1280 blocks
    deconv_quad_direct< 96, 64, 32, 2><<<dim3(16, 10,  8), 256, 0, stream>>>(A,  dw3, db3, Bb);
    // d4: R8's winning block count (1920 = 7.5/CU) with the coalesced 4x16 map
    deconv_quad_direct< 64, 48, 64, 4><<<dim3(64, 10,  3), 256, 0, stream>>>(Bb, dw4, db4, A);

    // fused 1x1 convs + geometry -> d_out
    final_fused_v2<<<dim3(128, 10), 256, 0, stream>>>(A, xyzw, xyzb, maskw, maskb, quat, out);
}

// Round 13
// 386.199 us; speedup vs baseline: 1.1469x; 1.1088x over previous
//
#include <hip/hip_runtime.h>

#define CDIV(a,b) (((a)+(b)-1)/(b))

typedef short short8v __attribute__((ext_vector_type(8)));
typedef float f32x4 __attribute__((ext_vector_type(4)));

__device__ __forceinline__ ushort f2bf(float v) {
    uint u = __float_as_uint(v);
    return (ushort)((u + 0x7FFF + ((u >> 16) & 1)) >> 16);
}

// ---------------------------------------------------------------------------
// conv0: 3->96, 64x64 -> 32x32, fully unrolled
// ---------------------------------------------------------------------------
__global__ __launch_bounds__(256) void conv3x3_c3(const float* __restrict__ in,
    const float* __restrict__ w, const float* __restrict__ bias, float* __restrict__ out)
{
    int idx = blockIdx.x * 256 + threadIdx.x;     // 10*96*32*32 = 983040 exact
    int ox = idx & 31; int t = idx >> 5;
    int oy = t & 31;   t >>= 5;
    int co = t % 96;   int b = t / 96;
    float acc = bias[co];
    const float* wp  = w + co * 27;
    const float* ipb = in + (size_t)b * 3 * 64 * 64;
    #pragma unroll
    for (int ci = 0; ci < 3; ++ci) {
        #pragma unroll
        for (int ky = 0; ky < 3; ++ky) {
            int iy = 2 * oy + ky;
            #pragma unroll
            for (int kx = 0; kx < 3; ++kx) {
                int ix = 2 * ox + kx;
                if (iy < 64 && ix < 64)
                    acc = fmaf(wp[ci * 9 + ky * 3 + kx], ipb[(ci * 64 + iy) * 64 + ix], acc);
            }
        }
    }
    out[idx] = fmaxf(acc, 0.f);
}

// ---------------------------------------------------------------------------
// conv1: ci-split-K with LDS staging (unchanged)
// ---------------------------------------------------------------------------
template<int CIN,int COUT,int HIN,int WIN,int SPLITS,int CK,int CO_R>
__global__ __launch_bounds__(256) void conv_splitk_big(const float* __restrict__ in,
    const float* __restrict__ w, float* __restrict__ partial)
{
    constexpr int HOUT = HIN/2, WOUT = WIN/2;
    constexpr int SP = HOUT * WOUT;
    static_assert(SP == 256, "one output px per thread");
    constexpr int HP = HIN + 1, WP = WIN + 2;
    constexpr int CSL = CIN / SPLITS;
    constexpr int NCH = CSL / CK;
    static_assert(CSL % CK == 0, "CK must divide ci slice");
    constexpr int SELEM = CK * HP * WP;
    constexpr int NLD = (SELEM + 255) / 256;
    __shared__ float sb[SELEM];

    const int b = blockIdx.y, s = blockIdx.z;
    const int co_base = blockIdx.x * CO_R;
    const int oy = threadIdx.x >> 4, ox = threadIdx.x & 15;
    const int ci00 = s * CSL;
    const float* inb = in + (size_t)b * CIN * HIN * WIN;

    float rg[NLD];
    auto load_chunk = [&](int ci0) {
        #pragma unroll
        for (int j = 0; j < NLD; ++j) {
            int i = threadIdx.x + j * 256;
            float v = 0.f;
            if (i < SELEM) {
                int c = i % WP; int r = (i / WP) % HP; int cl = i / (WP * HP);
                if (r < HIN && c < WIN) v = inb[((size_t)(ci0 + cl) * HIN + r) * WIN + c];
            }
            rg[j] = v;
        }
    };
    load_chunk(ci00);

    float acc[CO_R] = {};
    for (int ch = 0; ch < NCH; ++ch) {
        #pragma unroll
        for (int j = 0; j < NLD; ++j) {
            int i = threadIdx.x + j * 256;
            if (i < SELEM) sb[i] = rg[j];
        }
        __syncthreads();
        if (ch + 1 < NCH) load_chunk(ci00 + (ch + 1) * CK);

        #pragma unroll
        for (int cl = 0; cl < CK; ++cl) {
            const float* sp = &sb[(cl * HP + 2 * oy) * WP + 2 * ox];
            float x[3][3];
            #pragma unroll
            for (int dy = 0; dy < 3; ++dy) {
                float2 f = *(const float2*)&sp[dy * WP];
                x[dy][0] = f.x; x[dy][1] = f.y; x[dy][2] = sp[dy * WP + 2];
            }
            int ci = ci00 + ch * CK + cl;
            const float* wp = w + ((size_t)co_base * CIN + ci) * 9;
            #pragma unroll
            for (int r = 0; r < CO_R; ++r) {
                const float* wr = wp + (size_t)r * CIN * 9;
                #pragma unroll
                for (int dy = 0; dy < 3; ++dy)
                    #pragma unroll
                    for (int dx = 0; dx < 3; ++dx)
                        acc[r] = fmaf(wr[dy * 3 + dx], x[dy][dx], acc[r]);
            }
        }
        __syncthreads();
    }
    #pragma unroll
    for (int r = 0; r < CO_R; ++r)
        partial[(((size_t)s * 10 + b) * COUT + co_base + r) * SP + threadIdx.x] = acc[r];
}

// ---------------------------------------------------------------------------
// conv2/conv3 split-K (unchanged)
// ---------------------------------------------------------------------------
template<int CIN,int COUT,int HIN,int WIN,int CK,int CO_R,int COS>
__global__ __launch_bounds__(256) void conv_small_splitk(const float* __restrict__ in,
    const float* __restrict__ w, float* __restrict__ partial)
{
    constexpr int HOUT = HIN/2, WOUT = WIN/2;
    constexpr int SP = HOUT * WOUT;
    static_assert(SP * COS == 256, "block covers SP x COS");
    constexpr int HP = HIN + 1, WP = WIN + 2;
    __shared__ float sb[CK * HP * WP];
    const int b = blockIdx.y;
    const int s = blockIdx.z;
    const int sp_i = threadIdx.x % SP;
    const int slot = threadIdx.x / SP;
    const int co_base = (blockIdx.x * COS + slot) * CO_R;
    const int oy = sp_i / WOUT, ox = sp_i % WOUT;
    const int ci0 = s * CK;
    const float* inb = in + (size_t)b * CIN * HIN * WIN;

    for (int i = threadIdx.x; i < CK * HP * WP; i += 256) {
        int c = i % WP; int r = (i / WP) % HP; int cl = i / (WP * HP);
        float v = 0.f;
        if (r < HIN && c < WIN) v = inb[((size_t)(ci0 + cl) * HIN + r) * WIN + c];
        sb[i] = v;
    }
    __syncthreads();

    float acc[CO_R] = {};
    #pragma unroll
    for (int cl = 0; cl < CK; ++cl) {
        const float* sp = &sb[(cl * HP + 2 * oy) * WP + 2 * ox];
        float x[3][3];
        #pragma unroll
        for (int dy = 0; dy < 3; ++dy) {
            float2 f = *(const float2*)&sp[dy * WP];
            x[dy][0] = f.x; x[dy][1] = f.y; x[dy][2] = sp[dy * WP + 2];
        }
        const float* wp = w + ((size_t)co_base * CIN + (ci0 + cl)) * 9;
        #pragma unroll
        for (int r = 0; r < CO_R; ++r) {
            const float* wr = wp + (size_t)r * CIN * 9;
            #pragma unroll
            for (int dy = 0; dy < 3; ++dy)
                #pragma unroll
                for (int dx = 0; dx < 3; ++dx)
                    acc[r] = fmaf(wr[dy * 3 + dx], x[dy][dx], acc[r]);
        }
    }
    #pragma unroll
    for (int r = 0; r < CO_R; ++r)
        partial[(((size_t)s * 10 + b) * COUT + co_base + r) * SP + sp_i] = acc[r];
}

template<int COUT,int SP,int S>
__global__ void conv_reduce_relu(const float* __restrict__ partial, const float* __restrict__ bias,
                                 float* __restrict__ out, int total)
{
    int i = blockIdx.x * 256 + threadIdx.x;
    if (i >= total) return;
    int sp = i % SP; int co = (i / SP) % COUT; int b = i / (SP * COUT);
    float acc = bias[co];
    #pragma unroll
    for (int s = 0; s < S; ++s) acc += partial[(((size_t)s * 10 + b) * COUT + co) * SP + sp];
    out[i] = fmaxf(acc, 0.f);
}

// ---------------------------------------------------------------------------
// d0/d1 split-K quad (unchanged)
// ---------------------------------------------------------------------------
template<int CIN,int COUT,int HIN,int CK,int CO_R,int QPW>
__global__ __launch_bounds__(256) void deconv_quad_splitk(const float* __restrict__ in,
    const float* __restrict__ w, float* __restrict__ partial)
{
    constexpr int CPW = 64 / QPW;
    constexpr int HP2 = HIN + 2;
    constexpr int SP = 4 * HIN * HIN;
    constexpr int WOUT = 2 * HIN;
    static_assert(QPW == HIN * HIN, "wave quads cover input plane");
    __shared__ float sb[CK * HP2 * HP2];
    const int b = blockIdx.y, s = blockIdx.z;
    const int lane = threadIdx.x & 63;
    const int wv = threadIdx.x >> 6;
    const int q = lane % QPW;
    const int co_off = lane / QPW;
    const int t = q / HIN, u = q % HIN;
    const int co_base = (blockIdx.x * 4 + wv) * CPW * CO_R + co_off * CO_R;
    const int ci0 = s * CK;
    const float* inb = in + (size_t)b * CIN * HIN * HIN;

    for (int i = threadIdx.x; i < CK * HP2 * HP2; i += 256) {
        int c = i % HP2; int r = (i / HP2) % HP2; int cl = i / (HP2 * HP2);
        int gr = r - 1, gc = c - 1;
        float v = 0.f;
        if (gr >= 0 && gr < HIN && gc >= 0 && gc < HIN)
            v = inb[((size_t)(ci0 + cl) * HIN + gr) * HIN + gc];
        sb[i] = v;
    }
    __syncthreads();

    float acc[CO_R][4] = {};
    #pragma unroll 4
    for (int cl = 0; cl < CK; ++cl) {
        const float* sp = &sb[(cl * HP2 + t) * HP2 + u];
        float x00 = sp[0],       x01 = sp[1],       x02 = sp[2];
        float x10 = sp[HP2],     x11 = sp[HP2+1],   x12 = sp[HP2+2];
        float x20 = sp[2*HP2],   x21 = sp[2*HP2+1], x22 = sp[2*HP2+2];
        const float* wp = w + ((size_t)(ci0 + cl) * COUT + co_base) * 16;
        #pragma unroll
        for (int r = 0; r < CO_R; ++r) {
            const float* W_ = wp + r * 16;
            acc[r][0] += W_[5]*x11 + W_[7]*x10 + W_[13]*x01 + W_[15]*x00;
            acc[r][1] += W_[4]*x12 + W_[6]*x11 + W_[12]*x02 + W_[14]*x01;
            acc[r][2] += W_[1]*x21 + W_[3]*x20 + W_[9]*x11  + W_[11]*x10;
            acc[r][3] += W_[0]*x22 + W_[2]*x21 + W_[8]*x12  + W_[10]*x11;
        }
    }
    #pragma unroll
    for (int r = 0; r < CO_R; ++r) {
        float* pp = partial + (((size_t)s * 10 + b) * COUT + co_base + r) * SP;
        pp[(2*t)   * WOUT + 2*u]     = acc[r][0];
        pp[(2*t)   * WOUT + 2*u + 1] = acc[r][1];
        pp[(2*t+1) * WOUT + 2*u]     = acc[r][2];
        pp[(2*t+1) * WOUT + 2*u + 1] = acc[r][3];
    }
}

// ---------------------------------------------------------------------------
// d2/d3 DIRECT (unchanged)
// ---------------------------------------------------------------------------
template<int CIN,int COUT,int HIN,int CO_R>
__global__ __launch_bounds__(256) void deconv_quad_direct(const float* __restrict__ in,
    const float* __restrict__ w, const float* __restrict__ bias, float* __restrict__ out)
{
    constexpr int WIN = HIN;
    constexpr int HOUT = 2 * HIN, WOUT = 2 * WIN;
    constexpr int TILES_W = WIN / 16;
    static_assert(WIN % 16 == 0 && HIN % 4 == 0, "4x16 quad tiles");

    const int lane = threadIdx.x & 63;
    const int wv   = __builtin_amdgcn_readfirstlane((int)(threadIdx.x >> 6));
    const int tile = blockIdx.x;
    const int tr = tile / TILES_W, tc = tile % TILES_W;
    const int b  = blockIdx.y;
    const int co_base = (blockIdx.z * 4 + wv) * CO_R;

    const int t = tr * 4 + (lane >> 4);
    const int u = tc * 16 + (lane & 15);
    const bool mr0 = t > 0, mr2 = t < HIN - 1, mc0 = u > 0, mc2 = u < WIN - 1;
    const int tm = mr0 ? t - 1 : t, tp = mr2 ? t + 1 : t;
    const int um = mc0 ? u - 1 : u, up = mc2 ? u + 1 : u;
    const int o00 = tm*WIN+um, o01 = tm*WIN+u, o02 = tm*WIN+up;
    const int o10 = t *WIN+um, o11 = t *WIN+u, o12 = t *WIN+up;
    const int o20 = tp*WIN+um, o21 = tp*WIN+u, o22 = tp*WIN+up;

    const float* p = in + (size_t)b * CIN * HIN * WIN;
    float acc[CO_R][4] = {};

    #pragma unroll 2
    for (int ci = 0; ci < CIN; ++ci) {
        float x00 = p[o00], x01 = p[o01], x02 = p[o02];
        float x10 = p[o10], x11 = p[o11], x12 = p[o12];
        float x20 = p[o20], x21 = p[o21], x22 = p[o22];
        x00 = (mr0 && mc0) ? x00 : 0.f;
        x01 = mr0 ? x01 : 0.f;
        x02 = (mr0 && mc2) ? x02 : 0.f;
        x10 = mc0 ? x10 : 0.f;
        x12 = mc2 ? x12 : 0.f;
        x20 = (mr2 && mc0) ? x20 : 0.f;
        x21 = mr2 ? x21 : 0.f;
        x22 = (mr2 && mc2) ? x22 : 0.f;

        const float* wp = w + ((size_t)ci * COUT + co_base) * 16;   // wave-uniform
        #pragma unroll
        for (int r = 0; r < CO_R; ++r) {
            const float* W_ = wp + r * 16;
            acc[r][0] += W_[5]*x11 + W_[7]*x10 + W_[13]*x01 + W_[15]*x00;
            acc[r][1] += W_[4]*x12 + W_[6]*x11 + W_[12]*x02 + W_[14]*x01;
            acc[r][2] += W_[1]*x21 + W_[3]*x20 + W_[9]*x11  + W_[11]*x10;
            acc[r][3] += W_[0]*x22 + W_[2]*x21 + W_[8]*x12  + W_[10]*x11;
        }
        p += HIN * WIN;
    }

    #pragma unroll
    for (int r = 0; r < CO_R; ++r) {
        int co = co_base + r;
        float bi = bias[co];
        float* ob = out + (((size_t)b * COUT + co) * HOUT + 2 * t) * WOUT + 2 * u;
        float2 v0, v1;
        v0.x = fmaxf(acc[r][0] + bi, 0.f);
        v0.y = fmaxf(acc[r][1] + bi, 0.f);
        v1.x = fmaxf(acc[r][2] + bi, 0.f);
        v1.y = fmaxf(acc[r][3] + bi, 0.f);
        *(float2*)ob = v0;
        *(float2*)&ob[WOUT] = v1;
    }
}

// ---------------------------------------------------------------------------
// d4 MFMA path. Parity q=(py,px): out_q[co][t,u] = sum_k A_q[co][k]*B[k][t,u],
// k = tap*64+ci (K=256), tap offsets dy=py-(tap>>1), dx=px-(tap&1),
// A_q[co][tap*64+ci] = w[((ci*48+co)*16)+widx[q][tap]].
// prep_wA packs A into mfma_16x16x32_bf16 fragment order:
//   frag(q,m,s): lane l -> row co=m*16+(l&15), k=s*32+(l>>4)*8+e.
// ---------------------------------------------------------------------------
__global__ __launch_bounds__(256) void prep_wA(const float* __restrict__ w, ushort* __restrict__ Abuf)
{
    int idx = blockIdx.x * 256 + threadIdx.x;          // 4*3*8*64*8 = 49152
    if (idx >= 49152) return;
    int e = idx & 7; int t2 = idx >> 3;
    int lane = t2 & 63; t2 >>= 6;
    int s = t2 & 7; t2 >>= 3;
    int m = t2 % 3; int q = t2 / 3;
    int co = m * 16 + (lane & 15);
    int k = s * 32 + (lane >> 4) * 8 + e;
    int tap = k >> 6, ci = k & 63;
    const int widx[4][4] = {{5,7,13,15},{4,6,12,14},{1,3,9,11},{0,2,8,10}};
    float v = w[((size_t)ci * 48 + co) * 16 + widx[q][tap]];
    Abuf[idx] = f2bf(v);
}

// grid (64 tiles, 10 b, 2 zq): block = 8x8 input-position tile, q in {2zq,2zq+1},
// 4 waves: wave w owns n-frag w (16 positions) x 3 m-frags x 2 q. LDS: bf16
// input tile [100 pos][64 ci] stride 72 (16B-aligned ds_read_b128 B-frags).
__global__ __launch_bounds__(256) void deconv4_mfma(const float* __restrict__ X,
    const ushort* __restrict__ Abuf, const float* __restrict__ bias, float* __restrict__ out)
{
    __shared__ __align__(16) ushort Xs[100 * 72];
    __shared__ float sbias[48];
    const int tid = threadIdx.x;
    const int t0 = (blockIdx.x >> 3) * 8, u0 = (blockIdx.x & 7) * 8;
    const int b = blockIdx.y, zq = blockIdx.z;

    const float* Xb = X + (size_t)b * 64 * 64 * 64;
    #pragma unroll
    for (int j = 0; j < 25; ++j) {
        int i = tid + j * 256;                         // 6400 = 64ci x 100pos
        int ci = i / 100, p = i % 100;
        int r = p / 10, c = p % 10;
        int gt = t0 - 1 + r, gu = u0 - 1 + c;
        float v = 0.f;
        if (gt >= 0 && gt < 64 && gu >= 0 && gu < 64)
            v = Xb[((size_t)ci * 64 + gt) * 64 + gu];
        Xs[p * 72 + ci] = f2bf(v);
    }
    if (tid < 48) sbias[tid] = bias[tid];
    __syncthreads();

    const int w = tid >> 6, lane = tid & 63;
    const int ncol = lane & 15, kg = lane >> 4;
    const int r_n = 2 * w + (ncol >> 3), c_n = ncol & 7;

    #pragma unroll
    for (int qz = 0; qz < 2; ++qz) {
        const int q = zq * 2 + qz;
        const int py = q >> 1, px = q & 1;
        int ptap[4];
        #pragma unroll
        for (int tp = 0; tp < 4; ++tp) {
            int dy = py - (tp >> 1);
            int dx = px - (tp & 1);
            ptap[tp] = ((r_n + 1 + dy) * 10 + (c_n + 1 + dx)) * 72;
        }
        #pragma unroll
        for (int m = 0; m < 3; ++m) {
            f32x4 acc = {0.f, 0.f, 0.f, 0.f};
            const ushort* ab = Abuf + ((size_t)((q * 3 + m) * 8) * 64 + lane) * 8;
            #pragma unroll
            for (int s = 0; s < 8; ++s) {
                short8v a = *(const short8v*)(ab + (size_t)s * 64 * 8);
                int ci0 = (s & 1) * 32 + kg * 8;
                short8v bf = *(const short8v*)(&Xs[ptap[s >> 1] + ci0]);
                acc = __builtin_amdgcn_mfma_f32_16x16x32_bf16(a, bf, acc, 0, 0, 0);
            }
            int t = t0 + r_n, u = u0 + c_n;
            size_t base = ((size_t)(b * 48 + m * 16 + kg * 4) * 128 + (2 * t + py)) * 128 + (2 * u + px);
            #pragma unroll
            for (int jj = 0; jj < 4; ++jj) {
                float v = acc[jj] + sbias[m * 16 + kg * 4 + jj];
                out[base + (size_t)jj * 16384] = fmaxf(v, 0.f);
            }
        }
    }
}

// ---------------------------------------------------------------------------
// Split-K FC (unchanged)
// ---------------------------------------------------------------------------
template<int KC>
__global__ __launch_bounds__(256) void fc_splitk(const float* __restrict__ in,
    const float* __restrict__ W, float* __restrict__ partial, int K, int N)
{
    __shared__ float s_in[10 * KC];
    const int o = blockIdx.x * 256 + threadIdx.x;
    const int k0 = blockIdx.y * KC;
    for (int i = threadIdx.x; i < 10 * KC; i += 256) {
        int b = i / KC, k = i % KC;
        s_in[i] = in[(size_t)b * K + k0 + k];
    }
    __syncthreads();

    float acc[10];
    #pragma unroll
    for (int b = 0; b < 10; ++b) acc[b] = 0.f;
    const float* wp = W + (size_t)k0 * N + o;
    #pragma unroll 4
    for (int k = 0; k < KC; ++k) {
        float wv = wp[(size_t)k * N];
        #pragma unroll
        for (int b = 0; b < 10; ++b) acc[b] = fmaf(wv, s_in[b * KC + k], acc[b]);
    }
    float* pp = partial + ((size_t)blockIdx.y * 10) * N + o;
    #pragma unroll
    for (int b = 0; b < 10; ++b) pp[(size_t)b * N] = acc[b];
}

__global__ void fc_reduce_relu(const float* __restrict__ partial, const float* __restrict__ bias,
                               float* __restrict__ out, int N, int S)
{
    int i = blockIdx.x * 256 + threadIdx.x;
    if (i >= 10 * N) return;
    int o = i % N, b = i / N;
    float acc = bias[o];
    for (int s = 0; s < S; ++s) acc += partial[((size_t)s * 10 + b) * N + o];
    out[(size_t)b * N + o] = fmaxf(acc, 0.f);
}

// ---------------------------------------------------------------------------
// Final fused: 1x1 convs + geometry (unchanged)
// ---------------------------------------------------------------------------
__global__ __launch_bounds__(256) void final_fused_v2(const float* __restrict__ h,
    const float* __restrict__ xyzw, const float* __restrict__ xyzb,
    const float* __restrict__ maskw, const float* __restrict__ maskb,
    const float* __restrict__ quat, float* __restrict__ out)
{
    const int V = 8, HW = 128 * 128, C = 48, Bn = 10, VHW = V * HW;
    __shared__ float4 sh[48 * 32];
    int b = blockIdx.y, tile = blockIdx.x;
    const float4* hb = (const float4*)h;
    for (int i = threadIdx.x; i < C * 32; i += 256) {
        int ci = i >> 5, p = i & 31;
        sh[i] = hb[(size_t)(b * C + ci) * (HW / 4) + tile * 32 + p];
    }
    __syncthreads();

    int pl = threadIdx.x & 31, v = threadIdx.x >> 5;
    float4 xr = {0,0,0,0}, yr = {0,0,0,0}, zr = {0,0,0,0}, mm = {0,0,0,0};
    const float* wx = xyzw + (size_t)(v * 3 + 0) * C;
    const float* wy = xyzw + (size_t)(v * 3 + 1) * C;
    const float* wz = xyzw + (size_t)(v * 3 + 2) * C;
    const float* wm = maskw + (size_t)v * C;
    for (int ci = 0; ci < C; ++ci) {
        float4 hv = sh[ci * 32 + pl];
        float a;
        a = wx[ci]; xr.x += a*hv.x; xr.y += a*hv.y; xr.z += a*hv.z; xr.w += a*hv.w;
        a = wy[ci]; yr.x += a*hv.x; yr.y += a*hv.y; yr.z += a*hv.z; yr.w += a*hv.w;
        a = wz[ci]; zr.x += a*hv.x; zr.y += a*hv.y; zr.z += a*hv.z; zr.w += a*hv.w;
        a = wm[ci]; mm.x += a*hv.x; mm.y += a*hv.y; mm.z += a*hv.z; mm.w += a*hv.w;
    }
    float bxv = xyzb[v * 3 + 0], byv = xyzb[v * 3 + 1], bzv = xyzb[v * 3 + 2], bmv = maskb[v];

    float qw = quat[v*4+0], qx = quat[v*4+1], qy = quat[v*4+2], qz = quat[v*4+3];
    float R00 = 1.f - 2.f*(qy*qy + qz*qz), R01 = 2.f*(qx*qy - qw*qz), R02 = 2.f*(qx*qz + qw*qy);
    float R10 = 2.f*(qx*qy + qw*qz), R11 = 1.f - 2.f*(qx*qx + qz*qz), R12 = 2.f*(qy*qz - qw*qx);
    float R20 = 2.f*(qx*qz - qw*qy), R21 = 2.f*(qy*qz + qw*qx), R22 = 1.f - 2.f*(qx*qx + qy*qy);

    float4 o0, o1, o2, om;
    float* X = (float*)&xr; float* Y = (float*)&yr; float* Z = (float*)&zr; float* M = (float*)&mm;
    float* O0 = (float*)&o0; float* O1 = (float*)&o1; float* O2 = (float*)&o2; float* OM = (float*)&om;
    #pragma unroll
    for (int j = 0; j < 4; ++j) {
        float camX = (X[j] + bxv) * (1.f / 64.f) - 0.5f;
        float camY = -(Y[j] + byv) * (1.f / 64.f) + 0.5f;
        float camZ = -((Z[j] + bzv) + 1.0f);
        O0[j] = R00 * camX + R10 * camY + R20 * camZ;
        O1[j] = R01 * camX + R11 * camY + R21 * camZ;
        O2[j] = R02 * camX + R12 * camY + R22 * camZ;
        OM[j] = M[j] + bmv;
    }

    size_t o = (size_t)v * HW + tile * 128 + pl * 4;
    float4* op = (float4*)out;
    op[((size_t)(b * 3 + 0) * VHW + o) >> 2] = o0;
    op[((size_t)(b * 3 + 1) * VHW + o) >> 2] = o1;
    op[((size_t)(b * 3 + 2) * VHW + o) >> 2] = o2;
    op[((size_t)Bn * 3 * VHW + (size_t)b * VHW + o) >> 2] = om;
}

// ---------------------------------------------------------------------------

extern "C" void kernel_launch(void* const* d_in, const int* in_sizes, int n_in,
                              void* d_out, int out_size, void* d_ws, size_t ws_size,
                              hipStream_t stream)
{
    const float* x    = (const float*)d_in[0];
    const float* ew0  = (const float*)d_in[1];
    const float* eb0  = (const float*)d_in[2];
    const float* ew1  = (const float*)d_in[3];
    const float* eb1  = (const float*)d_in[4];
    const float* ew2  = (const float*)d_in[5];
    const float* eb2  = (const float*)d_in[6];
    const float* ew3  = (const float*)d_in[7];
    const float* eb3  = (const float*)d_in[8];
    const float* efw  = (const float*)d_in[9];
    const float* efb  = (const float*)d_in[10];
    const float* dfw  = (const float*)d_in[11];
    const float* dfb  = (const float*)d_in[12];
    const float* dw0  = (const float*)d_in[13];
    const float* db0  = (const float*)d_in[14];
    const float* dw1  = (const float*)d_in[15];
    const float* db1  = (const float*)d_in[16];
    const float* dw2  = (const float*)d_in[17];
    const float* db2  = (const float*)d_in[18];
    const float* dw3  = (const float*)d_in[19];
    const float* db3  = (const float*)d_in[20];
    const float* dw4  = (const float*)d_in[21];
    const float* db4  = (const float*)d_in[22];
    const float* xyzw = (const float*)d_in[23];
    const float* xyzb = (const float*)d_in[24];
    const float* maskw= (const float*)d_in[25];
    const float* maskb= (const float*)d_in[26];
    const float* quat = (const float*)d_in[27];
    float* out = (float*)d_out;

    float* A   = (float*)d_ws;
    float* Bb  = A + 7864320;
    float* P1  = A;                 // fc1 partials
    float* L   = A + 1000000;       // latent
    float* P2  = Bb + 1000000;      // fc2 partials
    float* H0  = Bb;                // fc2 out
    float* PC1 = A + 2000000;       // conv1 partials 5,242,880
    float* PC2 = A + 2000000;       // conv2 partials
    float* PC3 = Bb + 500000;       // conv3 partials
    float* PD0 = A + 2000000;       // d0 partials
    float* PD1 = Bb + 1000000;      // d1 partials
    ushort* Abuf = (ushort*)(Bb + 2700000);   // d4 bf16 A-frags, 96 KB (past d3 out 2,621,440)

    const int TB = 256;

    // d4 weight prep (independent of activations)
    prep_wA<<<192, 256, 0, stream>>>(dw4, Abuf);

    // encoder
    conv3x3_c3<<<3840, 256, 0, stream>>>(x, ew0, eb0, A);
    conv_splitk_big<96,128,32,32,16,6,16><<<dim3(8,10,16), 256, 0, stream>>>(A, ew1, PC1);
    conv_reduce_relu<128,256,16><<<CDIV(327680,TB), TB, 0, stream>>>(PC1, eb1, Bb, 327680);
    conv_small_splitk<128,192,16,16,16,3,4><<<dim3(16,10,8), 256, 0, stream>>>(Bb, ew2, PC2);
    conv_reduce_relu<192,64,8><<<CDIV(122880,TB), TB, 0, stream>>>(PC2, eb2, A, 122880);
    conv_small_splitk<192,256,8,8,16,1,16><<<dim3(16,10,12), 256, 0, stream>>>(A, ew3, PC3);
    conv_reduce_relu<256,16,12><<<CDIV(40960,TB), TB, 0, stream>>>(PC3, eb3, Bb, 40960);

    // fc
    fc_splitk<32><<<dim3(2, 128), 256, 0, stream>>>(Bb, efw, P1, 4096, 512);
    fc_reduce_relu<<<CDIV(10 * 512, TB), TB, 0, stream>>>(P1, efb, L, 512, 128);
    fc_splitk<32><<<dim3(16, 16), 256, 0, stream>>>(L, dfw, P2, 512, 4096);
    fc_reduce_relu<<<CDIV(10 * 4096, TB), TB, 0, stream>>>(P2, dfb, H0, 4096, 16);

    // decoder
    deconv_quad_splitk<256,192,4,64,1,16><<<dim3(12,10,4), 256, 0, stream>>>(H0, dw0, PD0);
    conv_reduce_relu<192,64,4><<<CDIV(122880,TB), TB, 0, stream>>>(PD0, db0, A, 122880);
    deconv_quad_splitk<192,128,8,48,2,64><<<dim3(16,10,4), 256, 0, stream>>>(A, dw1, PD1);
    conv_reduce_relu<128,256,4><<<CDIV(327680,TB), TB, 0, stream>>>(PD1, db1, Bb, 327680);

    deconv_quad_direct<128, 96, 16, 2><<<dim3( 4, 10, 12), 256, 0, stream>>>(Bb, dw2, db2, A);
    deconv_quad_direct< 96, 64, 32, 2><<<dim3(16, 10,  8), 256, 0, stream>>>(A,  dw3, db3, Bb);

    // d4: bf16 MFMA implicit GEMM (1280 blocks = 5/CU)
    deconv4_mfma<<<dim3(64, 10, 2), 256, 0, stream>>>(Bb, Abuf, db4, A);

    // fused 1x1 convs + geometry -> d_out
    final_fused_v2<<<dim3(128, 10), 256, 0, stream>>>(A, xyzw, xyzb, maskw, maskb, quat, out);
}

// Round 14
// 355.515 us; speedup vs baseline: 1.2458x; 1.0863x over previous
//
#include <hip/hip_runtime.h>

#define CDIV(a,b) (((a)+(b)-1)/(b))

typedef short short8v __attribute__((ext_vector_type(8)));
typedef float f32x4 __attribute__((ext_vector_type(4)));

__device__ __forceinline__ ushort f2bf(float v) {
    uint u = __float_as_uint(v);
    return (ushort)((u + 0x7FFF + ((u >> 16) & 1)) >> 16);
}

// ---------------------------------------------------------------------------
// conv0: 3->96, 64x64 -> 32x32, fully unrolled
// ---------------------------------------------------------------------------
__global__ __launch_bounds__(256) void conv3x3_c3(const float* __restrict__ in,
    const float* __restrict__ w, const float* __restrict__ bias, float* __restrict__ out)
{
    int idx = blockIdx.x * 256 + threadIdx.x;     // 10*96*32*32 = 983040 exact
    int ox = idx & 31; int t = idx >> 5;
    int oy = t & 31;   t >>= 5;
    int co = t % 96;   int b = t / 96;
    float acc = bias[co];
    const float* wp  = w + co * 27;
    const float* ipb = in + (size_t)b * 3 * 64 * 64;
    #pragma unroll
    for (int ci = 0; ci < 3; ++ci) {
        #pragma unroll
        for (int ky = 0; ky < 3; ++ky) {
            int iy = 2 * oy + ky;
            #pragma unroll
            for (int kx = 0; kx < 3; ++kx) {
                int ix = 2 * ox + kx;
                if (iy < 64 && ix < 64)
                    acc = fmaf(wp[ci * 9 + ky * 3 + kx], ipb[(ci * 64 + iy) * 64 + ix], acc);
            }
        }
    }
    out[idx] = fmaxf(acc, 0.f);
}

// ---------------------------------------------------------------------------
// conv1: ci-split-K with LDS staging (unchanged)
// ---------------------------------------------------------------------------
template<int CIN,int COUT,int HIN,int WIN,int SPLITS,int CK,int CO_R>
__global__ __launch_bounds__(256) void conv_splitk_big(const float* __restrict__ in,
    const float* __restrict__ w, float* __restrict__ partial)
{
    constexpr int HOUT = HIN/2, WOUT = WIN/2;
    constexpr int SP = HOUT * WOUT;
    static_assert(SP == 256, "one output px per thread");
    constexpr int HP = HIN + 1, WP = WIN + 2;
    constexpr int CSL = CIN / SPLITS;
    constexpr int NCH = CSL / CK;
    static_assert(CSL % CK == 0, "CK must divide ci slice");
    constexpr int SELEM = CK * HP * WP;
    constexpr int NLD = (SELEM + 255) / 256;
    __shared__ float sb[SELEM];

    const int b = blockIdx.y, s = blockIdx.z;
    const int co_base = blockIdx.x * CO_R;
    const int oy = threadIdx.x >> 4, ox = threadIdx.x & 15;
    const int ci00 = s * CSL;
    const float* inb = in + (size_t)b * CIN * HIN * WIN;

    float rg[NLD];
    auto load_chunk = [&](int ci0) {
        #pragma unroll
        for (int j = 0; j < NLD; ++j) {
            int i = threadIdx.x + j * 256;
            float v = 0.f;
            if (i < SELEM) {
                int c = i % WP; int r = (i / WP) % HP; int cl = i / (WP * HP);
                if (r < HIN && c < WIN) v = inb[((size_t)(ci0 + cl) * HIN + r) * WIN + c];
            }
            rg[j] = v;
        }
    };
    load_chunk(ci00);

    float acc[CO_R] = {};
    for (int ch = 0; ch < NCH; ++ch) {
        #pragma unroll
        for (int j = 0; j < NLD; ++j) {
            int i = threadIdx.x + j * 256;
            if (i < SELEM) sb[i] = rg[j];
        }
        __syncthreads();
        if (ch + 1 < NCH) load_chunk(ci00 + (ch + 1) * CK);

        #pragma unroll
        for (int cl = 0; cl < CK; ++cl) {
            const float* sp = &sb[(cl * HP + 2 * oy) * WP + 2 * ox];
            float x[3][3];
            #pragma unroll
            for (int dy = 0; dy < 3; ++dy) {
                float2 f = *(const float2*)&sp[dy * WP];
                x[dy][0] = f.x; x[dy][1] = f.y; x[dy][2] = sp[dy * WP + 2];
            }
            int ci = ci00 + ch * CK + cl;
            const float* wp = w + ((size_t)co_base * CIN + ci) * 9;
            #pragma unroll
            for (int r = 0; r < CO_R; ++r) {
                const float* wr = wp + (size_t)r * CIN * 9;
                #pragma unroll
                for (int dy = 0; dy < 3; ++dy)
                    #pragma unroll
                    for (int dx = 0; dx < 3; ++dx)
                        acc[r] = fmaf(wr[dy * 3 + dx], x[dy][dx], acc[r]);
            }
        }
        __syncthreads();
    }
    #pragma unroll
    for (int r = 0; r < CO_R; ++r)
        partial[(((size_t)s * 10 + b) * COUT + co_base + r) * SP + threadIdx.x] = acc[r];
}

// ---------------------------------------------------------------------------
// conv2/conv3 split-K (unchanged)
// ---------------------------------------------------------------------------
template<int CIN,int COUT,int HIN,int WIN,int CK,int CO_R,int COS>
__global__ __launch_bounds__(256) void conv_small_splitk(const float* __restrict__ in,
    const float* __restrict__ w, float* __restrict__ partial)
{
    constexpr int HOUT = HIN/2, WOUT = WIN/2;
    constexpr int SP = HOUT * WOUT;
    static_assert(SP * COS == 256, "block covers SP x COS");
    constexpr int HP = HIN + 1, WP = WIN + 2;
    __shared__ float sb[CK * HP * WP];
    const int b = blockIdx.y;
    const int s = blockIdx.z;
    const int sp_i = threadIdx.x % SP;
    const int slot = threadIdx.x / SP;
    const int co_base = (blockIdx.x * COS + slot) * CO_R;
    const int oy = sp_i / WOUT, ox = sp_i % WOUT;
    const int ci0 = s * CK;
    const float* inb = in + (size_t)b * CIN * HIN * WIN;

    for (int i = threadIdx.x; i < CK * HP * WP; i += 256) {
        int c = i % WP; int r = (i / WP) % HP; int cl = i / (WP * HP);
        float v = 0.f;
        if (r < HIN && c < WIN) v = inb[((size_t)(ci0 + cl) * HIN + r) * WIN + c];
        sb[i] = v;
    }
    __syncthreads();

    float acc[CO_R] = {};
    #pragma unroll
    for (int cl = 0; cl < CK; ++cl) {
        const float* sp = &sb[(cl * HP + 2 * oy) * WP + 2 * ox];
        float x[3][3];
        #pragma unroll
        for (int dy = 0; dy < 3; ++dy) {
            float2 f = *(const float2*)&sp[dy * WP];
            x[dy][0] = f.x; x[dy][1] = f.y; x[dy][2] = sp[dy * WP + 2];
        }
        const float* wp = w + ((size_t)co_base * CIN + (ci0 + cl)) * 9;
        #pragma unroll
        for (int r = 0; r < CO_R; ++r) {
            const float* wr = wp + (size_t)r * CIN * 9;
            #pragma unroll
            for (int dy = 0; dy < 3; ++dy)
                #pragma unroll
                for (int dx = 0; dx < 3; ++dx)
                    acc[r] = fmaf(wr[dy * 3 + dx], x[dy][dx], acc[r]);
        }
    }
    #pragma unroll
    for (int r = 0; r < CO_R; ++r)
        partial[(((size_t)s * 10 + b) * COUT + co_base + r) * SP + sp_i] = acc[r];
}

template<int COUT,int SP,int S>
__global__ void conv_reduce_relu(const float* __restrict__ partial, const float* __restrict__ bias,
                                 float* __restrict__ out, int total)
{
    int i = blockIdx.x * 256 + threadIdx.x;
    if (i >= total) return;
    int sp = i % SP; int co = (i / SP) % COUT; int b = i / (SP * COUT);
    float acc = bias[co];
    #pragma unroll
    for (int s = 0; s < S; ++s) acc += partial[(((size_t)s * 10 + b) * COUT + co) * SP + sp];
    out[i] = fmaxf(acc, 0.f);
}

// ---------------------------------------------------------------------------
// d0/d1 split-K quad (unchanged)
// ---------------------------------------------------------------------------
template<int CIN,int COUT,int HIN,int CK,int CO_R,int QPW>
__global__ __launch_bounds__(256) void deconv_quad_splitk(const float* __restrict__ in,
    const float* __restrict__ w, float* __restrict__ partial)
{
    constexpr int CPW = 64 / QPW;
    constexpr int HP2 = HIN + 2;
    constexpr int SP = 4 * HIN * HIN;
    constexpr int WOUT = 2 * HIN;
    static_assert(QPW == HIN * HIN, "wave quads cover input plane");
    __shared__ float sb[CK * HP2 * HP2];
    const int b = blockIdx.y, s = blockIdx.z;
    const int lane = threadIdx.x & 63;
    const int wv = threadIdx.x >> 6;
    const int q = lane % QPW;
    const int co_off = lane / QPW;
    const int t = q / HIN, u = q % HIN;
    const int co_base = (blockIdx.x * 4 + wv) * CPW * CO_R + co_off * CO_R;
    const int ci0 = s * CK;
    const float* inb = in + (size_t)b * CIN * HIN * HIN;

    for (int i = threadIdx.x; i < CK * HP2 * HP2; i += 256) {
        int c = i % HP2; int r = (i / HP2) % HP2; int cl = i / (HP2 * HP2);
        int gr = r - 1, gc = c - 1;
        float v = 0.f;
        if (gr >= 0 && gr < HIN && gc >= 0 && gc < HIN)
            v = inb[((size_t)(ci0 + cl) * HIN + gr) * HIN + gc];
        sb[i] = v;
    }
    __syncthreads();

    float acc[CO_R][4] = {};
    #pragma unroll 4
    for (int cl = 0; cl < CK; ++cl) {
        const float* sp = &sb[(cl * HP2 + t) * HP2 + u];
        float x00 = sp[0],       x01 = sp[1],       x02 = sp[2];
        float x10 = sp[HP2],     x11 = sp[HP2+1],   x12 = sp[HP2+2];
        float x20 = sp[2*HP2],   x21 = sp[2*HP2+1], x22 = sp[2*HP2+2];
        const float* wp = w + ((size_t)(ci0 + cl) * COUT + co_base) * 16;
        #pragma unroll
        for (int r = 0; r < CO_R; ++r) {
            const float* W_ = wp + r * 16;
            acc[r][0] += W_[5]*x11 + W_[7]*x10 + W_[13]*x01 + W_[15]*x00;
            acc[r][1] += W_[4]*x12 + W_[6]*x11 + W_[12]*x02 + W_[14]*x01;
            acc[r][2] += W_[1]*x21 + W_[3]*x20 + W_[9]*x11  + W_[11]*x10;
            acc[r][3] += W_[0]*x22 + W_[2]*x21 + W_[8]*x12  + W_[10]*x11;
        }
    }
    #pragma unroll
    for (int r = 0; r < CO_R; ++r) {
        float* pp = partial + (((size_t)s * 10 + b) * COUT + co_base + r) * SP;
        pp[(2*t)   * WOUT + 2*u]     = acc[r][0];
        pp[(2*t)   * WOUT + 2*u + 1] = acc[r][1];
        pp[(2*t+1) * WOUT + 2*u]     = acc[r][2];
        pp[(2*t+1) * WOUT + 2*u + 1] = acc[r][3];
    }
}

// ---------------------------------------------------------------------------
// d2 DIRECT (unchanged)
// ---------------------------------------------------------------------------
template<int CIN,int COUT,int HIN,int CO_R>
__global__ __launch_bounds__(256) void deconv_quad_direct(const float* __restrict__ in,
    const float* __restrict__ w, const float* __restrict__ bias, float* __restrict__ out)
{
    constexpr int WIN = HIN;
    constexpr int HOUT = 2 * HIN, WOUT = 2 * WIN;
    constexpr int TILES_W = WIN / 16;
    static_assert(WIN % 16 == 0 && HIN % 4 == 0, "4x16 quad tiles");

    const int lane = threadIdx.x & 63;
    const int wv   = __builtin_amdgcn_readfirstlane((int)(threadIdx.x >> 6));
    const int tile = blockIdx.x;
    const int tr = tile / TILES_W, tc = tile % TILES_W;
    const int b  = blockIdx.y;
    const int co_base = (blockIdx.z * 4 + wv) * CO_R;

    const int t = tr * 4 + (lane >> 4);
    const int u = tc * 16 + (lane & 15);
    const bool mr0 = t > 0, mr2 = t < HIN - 1, mc0 = u > 0, mc2 = u < WIN - 1;
    const int tm = mr0 ? t - 1 : t, tp = mr2 ? t + 1 : t;
    const int um = mc0 ? u - 1 : u, up = mc2 ? u + 1 : u;
    const int o00 = tm*WIN+um, o01 = tm*WIN+u, o02 = tm*WIN+up;
    const int o10 = t *WIN+um, o11 = t *WIN+u, o12 = t *WIN+up;
    const int o20 = tp*WIN+um, o21 = tp*WIN+u, o22 = tp*WIN+up;

    const float* p = in + (size_t)b * CIN * HIN * WIN;
    float acc[CO_R][4] = {};

    #pragma unroll 2
    for (int ci = 0; ci < CIN; ++ci) {
        float x00 = p[o00], x01 = p[o01], x02 = p[o02];
        float x10 = p[o10], x11 = p[o11], x12 = p[o12];
        float x20 = p[o20], x21 = p[o21], x22 = p[o22];
        x00 = (mr0 && mc0) ? x00 : 0.f;
        x01 = mr0 ? x01 : 0.f;
        x02 = (mr0 && mc2) ? x02 : 0.f;
        x10 = mc0 ? x10 : 0.f;
        x12 = mc2 ? x12 : 0.f;
        x20 = (mr2 && mc0) ? x20 : 0.f;
        x21 = mr2 ? x21 : 0.f;
        x22 = (mr2 && mc2) ? x22 : 0.f;

        const float* wp = w + ((size_t)ci * COUT + co_base) * 16;   // wave-uniform
        #pragma unroll
        for (int r = 0; r < CO_R; ++r) {
            const float* W_ = wp + r * 16;
            acc[r][0] += W_[5]*x11 + W_[7]*x10 + W_[13]*x01 + W_[15]*x00;
            acc[r][1] += W_[4]*x12 + W_[6]*x11 + W_[12]*x02 + W_[14]*x01;
            acc[r][2] += W_[1]*x21 + W_[3]*x20 + W_[9]*x11  + W_[11]*x10;
            acc[r][3] += W_[0]*x22 + W_[2]*x21 + W_[8]*x12  + W_[10]*x11;
        }
        p += HIN * WIN;
    }

    #pragma unroll
    for (int r = 0; r < CO_R; ++r) {
        int co = co_base + r;
        float bi = bias[co];
        float* ob = out + (((size_t)b * COUT + co) * HOUT + 2 * t) * WOUT + 2 * u;
        float2 v0, v1;
        v0.x = fmaxf(acc[r][0] + bi, 0.f);
        v0.y = fmaxf(acc[r][1] + bi, 0.f);
        v1.x = fmaxf(acc[r][2] + bi, 0.f);
        v1.y = fmaxf(acc[r][3] + bi, 0.f);
        *(float2*)ob = v0;
        *(float2*)&ob[WOUT] = v1;
    }
}

// ---------------------------------------------------------------------------
// Generalized MFMA deconv prep: pack A_q[co][k] (k = tap*CIN+ci, K=4*CIN) into
// mfma_16x16x32_bf16 fragment order: frag(q,m,s): lane l, elem e ->
// co = m*16+(l&15), k = s*32+(l>>4)*8+e. widx[q][tap] maps to the 4x4 kernel.
// ---------------------------------------------------------------------------
template<int CIN,int COUT>
__global__ __launch_bounds__(256) void prep_wA_g(const float* __restrict__ w, ushort* __restrict__ Abuf)
{
    constexpr int MFR = COUT / 16, NSL = CIN / 8;
    constexpr int TOTAL = 4 * MFR * NSL * 64 * 8;
    int idx = blockIdx.x * 256 + threadIdx.x;
    if (idx >= TOTAL) return;
    int e = idx & 7; int t2 = idx >> 3;
    int lane = t2 & 63; t2 >>= 6;
    int s = t2 % NSL; t2 /= NSL;
    int m = t2 % MFR; int q = t2 / MFR;
    int co = m * 16 + (lane & 15);
    int k = s * 32 + (lane >> 4) * 8 + e;
    int tap = k / CIN, ci = k % CIN;
    const int widx[4][4] = {{5,7,13,15},{4,6,12,14},{1,3,9,11},{0,2,8,10}};
    float v = w[((size_t)ci * COUT + co) * 16 + widx[q][tap]];
    Abuf[idx] = f2bf(v);
}

// Generalized MFMA deconv main: grid (tiles, 10, z). Block = 8x8 input tile.
// QPB q per block (z covers 4/QPB groups). Wave w owns n-frag w; loops MFR
// m-frags x NSL k-slices. LDS [100][CIN] bf16, stride CIN+8.
template<int CIN,int COUT,int HIN,int QPB>
__global__ __launch_bounds__(256) void deconv_mfma_g(const float* __restrict__ X,
    const ushort* __restrict__ Abuf, const float* __restrict__ bias, float* __restrict__ out)
{
    constexpr int MFR = COUT / 16, NSL = CIN / 8, STR = CIN + 8;
    constexpr int WOUT = 2 * HIN, PLANE = 4 * HIN * HIN;
    __shared__ __align__(16) ushort Xs[100 * STR];
    __shared__ float sbias[COUT];
    const int tid = threadIdx.x;
    constexpr int TW = HIN / 8;
    const int t0 = (blockIdx.x / TW) * 8, u0 = (blockIdx.x % TW) * 8;
    const int b = blockIdx.y, zq = blockIdx.z;

    const float* Xb = X + (size_t)b * CIN * HIN * HIN;
    for (int i = tid; i < CIN * 100; i += 256) {
        int ci = i / 100, p = i % 100;
        int r = p / 10, c = p % 10;
        int gt = t0 - 1 + r, gu = u0 - 1 + c;
        float v = 0.f;
        if (gt >= 0 && gt < HIN && gu >= 0 && gu < HIN)
            v = Xb[((size_t)ci * HIN + gt) * HIN + gu];
        Xs[p * STR + ci] = f2bf(v);
    }
    if (tid < COUT) sbias[tid] = bias[tid];
    __syncthreads();

    const int w = tid >> 6, lane = tid & 63;
    const int ncol = lane & 15, kg = lane >> 4;
    const int r_n = 2 * w + (ncol >> 3), c_n = ncol & 7;

    #pragma unroll
    for (int qz = 0; qz < QPB; ++qz) {
        const int q = zq * QPB + qz;
        const int py = q >> 1, px = q & 1;
        int ptap[4];
        #pragma unroll
        for (int tp = 0; tp < 4; ++tp) {
            int dy = py - (tp >> 1);
            int dx = px - (tp & 1);
            ptap[tp] = ((r_n + 1 + dy) * 10 + (c_n + 1 + dx)) * STR;
        }
        #pragma unroll
        for (int m = 0; m < MFR; ++m) {
            f32x4 acc = {0.f, 0.f, 0.f, 0.f};
            const ushort* ab = Abuf + (((size_t)(q * MFR + m) * NSL) * 64 + lane) * 8;
            #pragma unroll
            for (int s = 0; s < NSL; ++s) {
                short8v a = *(const short8v*)(ab + (size_t)s * 64 * 8);
                int tap = (s * 32) / CIN;
                int ci0 = (s * 32) % CIN + kg * 8;
                short8v bf = *(const short8v*)(&Xs[ptap[tap] + ci0]);
                acc = __builtin_amdgcn_mfma_f32_16x16x32_bf16(a, bf, acc, 0, 0, 0);
            }
            int t = t0 + r_n, u = u0 + c_n;
            size_t base = ((size_t)(b * COUT + m * 16 + kg * 4) * (2 * HIN) + (2 * t + py)) * WOUT + (2 * u + px);
            #pragma unroll
            for (int jj = 0; jj < 4; ++jj) {
                float v = acc[jj] + sbias[m * 16 + kg * 4 + jj];
                out[base + (size_t)jj * PLANE] = fmaxf(v, 0.f);
            }
        }
    }
}

// ---------------------------------------------------------------------------
// Split-K FC (unchanged)
// ---------------------------------------------------------------------------
template<int KC>
__global__ __launch_bounds__(256) void fc_splitk(const float* __restrict__ in,
    const float* __restrict__ W, float* __restrict__ partial, int K, int N)
{
    __shared__ float s_in[10 * KC];
    const int o = blockIdx.x * 256 + threadIdx.x;
    const int k0 = blockIdx.y * KC;
    for (int i = threadIdx.x; i < 10 * KC; i += 256) {
        int b = i / KC, k = i % KC;
        s_in[i] = in[(size_t)b * K + k0 + k];
    }
    __syncthreads();

    float acc[10];
    #pragma unroll
    for (int b = 0; b < 10; ++b) acc[b] = 0.f;
    const float* wp = W + (size_t)k0 * N + o;
    #pragma unroll 4
    for (int k = 0; k < KC; ++k) {
        float wv = wp[(size_t)k * N];
        #pragma unroll
        for (int b = 0; b < 10; ++b) acc[b] = fmaf(wv, s_in[b * KC + k], acc[b]);
    }
    float* pp = partial + ((size_t)blockIdx.y * 10) * N + o;
    #pragma unroll
    for (int b = 0; b < 10; ++b) pp[(size_t)b * N] = acc[b];
}

__global__ void fc_reduce_relu(const float* __restrict__ partial, const float* __restrict__ bias,
                               float* __restrict__ out, int N, int S)
{
    int i = blockIdx.x * 256 + threadIdx.x;
    if (i >= 10 * N) return;
    int o = i % N, b = i / N;
    float acc = bias[o];
    for (int s = 0; s < S; ++s) acc += partial[((size_t)s * 10 + b) * N + o];
    out[(size_t)b * N + o] = fmaxf(acc, 0.f);
}

// ---------------------------------------------------------------------------
// Final fused: 1x1 convs + geometry (unchanged)
// ---------------------------------------------------------------------------
__global__ __launch_bounds__(256) void final_fused_v2(const float* __restrict__ h,
    const float* __restrict__ xyzw, const float* __restrict__ xyzb,
    const float* __restrict__ maskw, const float* __restrict__ maskb,
    const float* __restrict__ quat, float* __restrict__ out)
{
    const int V = 8, HW = 128 * 128, C = 48, Bn = 10, VHW = V * HW;
    __shared__ float4 sh[48 * 32];
    int b = blockIdx.y, tile = blockIdx.x;
    const float4* hb = (const float4*)h;
    for (int i = threadIdx.x; i < C * 32; i += 256) {
        int ci = i >> 5, p = i & 31;
        sh[i] = hb[(size_t)(b * C + ci) * (HW / 4) + tile * 32 + p];
    }
    __syncthreads();

    int pl = threadIdx.x & 31, v = threadIdx.x >> 5;
    float4 xr = {0,0,0,0}, yr = {0,0,0,0}, zr = {0,0,0,0}, mm = {0,0,0,0};
    const float* wx = xyzw + (size_t)(v * 3 + 0) * C;
    const float* wy = xyzw + (size_t)(v * 3 + 1) * C;
    const float* wz = xyzw + (size_t)(v * 3 + 2) * C;
    const float* wm = maskw + (size_t)v * C;
    for (int ci = 0; ci < C; ++ci) {
        float4 hv = sh[ci * 32 + pl];
        float a;
        a = wx[ci]; xr.x += a*hv.x; xr.y += a*hv.y; xr.z += a*hv.z; xr.w += a*hv.w;
        a = wy[ci]; yr.x += a*hv.x; yr.y += a*hv.y; yr.z += a*hv.z; yr.w += a*hv.w;
        a = wz[ci]; zr.x += a*hv.x; zr.y += a*hv.y; zr.z += a*hv.z; zr.w += a*hv.w;
        a = wm[ci]; mm.x += a*hv.x; mm.y += a*hv.y; mm.z += a*hv.z; mm.w += a*hv.w;
    }
    float bxv = xyzb[v * 3 + 0], byv = xyzb[v * 3 + 1], bzv = xyzb[v * 3 + 2], bmv = maskb[v];

    float qw = quat[v*4+0], qx = quat[v*4+1], qy = quat[v*4+2], qz = quat[v*4+3];
    float R00 = 1.f - 2.f*(qy*qy + qz*qz), R01 = 2.f*(qx*qy - qw*qz), R02 = 2.f*(qx*qz + qw*qy);
    float R10 = 2.f*(qx*qy + qw*qz), R11 = 1.f - 2.f*(qx*qx + qz*qz), R12 = 2.f*(qy*qz - qw*qx);
    float R20 = 2.f*(qx*qz - qw*qy), R21 = 2.f*(qy*qz + qw*qx), R22 = 1.f - 2.f*(qx*qx + qy*qy);

    float4 o0, o1, o2, om;
    float* X = (float*)&xr; float* Y = (float*)&yr; float* Z = (float*)&zr; float* M = (float*)&mm;
    float* O0 = (float*)&o0; float* O1 = (float*)&o1; float* O2 = (float*)&o2; float* OM = (float*)&om;
    #pragma unroll
    for (int j = 0; j < 4; ++j) {
        float camX = (X[j] + bxv) * (1.f / 64.f) - 0.5f;
        float camY = -(Y[j] + byv) * (1.f / 64.f) + 0.5f;
        float camZ = -((Z[j] + bzv) + 1.0f);
        O0[j] = R00 * camX + R10 * camY + R20 * camZ;
        O1[j] = R01 * camX + R11 * camY + R21 * camZ;
        O2[j] = R02 * camX + R12 * camY + R22 * camZ;
        OM[j] = M[j] + bmv;
    }

    size_t o = (size_t)v * HW + tile * 128 + pl * 4;
    float4* op = (float4*)out;
    op[((size_t)(b * 3 + 0) * VHW + o) >> 2] = o0;
    op[((size_t)(b * 3 + 1) * VHW + o) >> 2] = o1;
    op[((size_t)(b * 3 + 2) * VHW + o) >> 2] = o2;
    op[((size_t)Bn * 3 * VHW + (size_t)b * VHW + o) >> 2] = om;
}

// ---------------------------------------------------------------------------

extern "C" void kernel_launch(void* const* d_in, const int* in_sizes, int n_in,
                              void* d_out, int out_size, void* d_ws, size_t ws_size,
                              hipStream_t stream)
{
    const float* x    = (const float*)d_in[0];
    const float* ew0  = (const float*)d_in[1];
    const float* eb0  = (const float*)d_in[2];
    const float* ew1  = (const float*)d_in[3];
    const float* eb1  = (const float*)d_in[4];
    const float* ew2  = (const float*)d_in[5];
    const float* eb2  = (const float*)d_in[6];
    const float* ew3  = (const float*)d_in[7];
    const float* eb3  = (const float*)d_in[8];
    const float* efw  = (const float*)d_in[9];
    const float* efb  = (const float*)d_in[10];
    const float* dfw  = (const float*)d_in[11];
    const float* dfb  = (const float*)d_in[12];
    const float* dw0  = (const float*)d_in[13];
    const float* db0  = (const float*)d_in[14];
    const float* dw1  = (const float*)d_in[15];
    const float* db1  = (const float*)d_in[16];
    const float* dw2  = (const float*)d_in[17];
    const float* db2  = (const float*)d_in[18];
    const float* dw3  = (const float*)d_in[19];
    const float* db3  = (const float*)d_in[20];
    const float* dw4  = (const float*)d_in[21];
    const float* db4  = (const float*)d_in[22];
    const float* xyzw = (const float*)d_in[23];
    const float* xyzb = (const float*)d_in[24];
    const float* maskw= (const float*)d_in[25];
    const float* maskb= (const float*)d_in[26];
    const float* quat = (const float*)d_in[27];
    float* out = (float*)d_out;

    float* A   = (float*)d_ws;
    float* Bb  = A + 7864320;
    float* P1  = A;                 // fc1 partials
    float* L   = A + 1000000 + 120000;  // latent (moved past Abuf3)
    float* P2  = Bb + 1000000;      // fc2 partials
    float* H0  = Bb;                // fc2 out
    float* PC1 = A + 2000000;       // conv1 partials 5,242,880
    float* PC2 = A + 2000000;       // conv2 partials
    float* PC3 = Bb + 500000;       // conv3 partials
    float* PD0 = A + 2000000;       // d0 partials
    float* PD1 = Bb + 1000000;      // d1 partials
    ushort* Abuf4 = (ushort*)(Bb + 2700000);  // d4 A-frags 49,152 ushorts (96 KB)
    ushort* Abuf3 = (ushort*)(A + 1000000);   // d3 A-frags 98,304 ushorts (192 KB), dead zone
                                              // (conv0 out < 983,040; PC1 >= 2,000,000; gone before d4 writes A)

    const int TB = 256;

    // weight prep (independent of activations)
    prep_wA_g<64,48><<<192, 256, 0, stream>>>(dw4, Abuf4);
    prep_wA_g<96,64><<<384, 256, 0, stream>>>(dw3, Abuf3);

    // encoder
    conv3x3_c3<<<3840, 256, 0, stream>>>(x, ew0, eb0, A);
    conv_splitk_big<96,128,32,32,16,6,16><<<dim3(8,10,16), 256, 0, stream>>>(A, ew1, PC1);
    conv_reduce_relu<128,256,16><<<CDIV(327680,TB), TB, 0, stream>>>(PC1, eb1, Bb, 327680);
    conv_small_splitk<128,192,16,16,16,3,4><<<dim3(16,10,8), 256, 0, stream>>>(Bb, ew2, PC2);
    conv_reduce_relu<192,64,8><<<CDIV(122880,TB), TB, 0, stream>>>(PC2, eb2, A, 122880);
    conv_small_splitk<192,256,8,8,16,1,16><<<dim3(16,10,12), 256, 0, stream>>>(A, ew3, PC3);
    conv_reduce_relu<256,16,12><<<CDIV(40960,TB), TB, 0, stream>>>(PC3, eb3, Bb, 40960);

    // fc
    fc_splitk<32><<<dim3(2, 128), 256, 0, stream>>>(Bb, efw, P1, 4096, 512);
    fc_reduce_relu<<<CDIV(10 * 512, TB), TB, 0, stream>>>(P1, efb, L, 512, 128);
    fc_splitk<32><<<dim3(16, 16), 256, 0, stream>>>(L, dfw, P2, 512, 4096);
    fc_reduce_relu<<<CDIV(10 * 4096, TB), TB, 0, stream>>>(P2, dfb, H0, 4096, 16);

    // decoder
    deconv_quad_splitk<256,192,4,64,1,16><<<dim3(12,10,4), 256, 0, stream>>>(H0, dw0, PD0);
    conv_reduce_relu<192,64,4><<<CDIV(122880,TB), TB, 0, stream>>>(PD0, db0, A, 122880);
    deconv_quad_splitk<192,128,8,48,2,64><<<dim3(16,10,4), 256, 0, stream>>>(A, dw1, PD1);
    conv_reduce_relu<128,256,4><<<CDIV(327680,TB), TB, 0, stream>>>(PD1, db1, Bb, 327680);

    deconv_quad_direct<128, 96, 16, 2><<<dim3( 4, 10, 12), 256, 0, stream>>>(Bb, dw2, db2, A);

    // d3: bf16 MFMA implicit GEMM, 1 q per block -> 640 blocks
    deconv_mfma_g<96, 64, 32, 1><<<dim3(16, 10, 4), 256, 0, stream>>>(A, Abuf3, db3, Bb);
    // d4: bf16 MFMA implicit GEMM, 2 q per block -> 1280 blocks
    deconv_mfma_g<64, 48, 64, 2><<<dim3(64, 10, 2), 256, 0, stream>>>(Bb, Abuf4, db4, A);

    // fused 1x1 convs + geometry -> d_out
    final_fused_v2<<<dim3(128, 10), 256, 0, stream>>>(A, xyzw, xyzb, maskw, maskb, quat, out);
}

// Round 15
// 331.970 us; speedup vs baseline: 1.3342x; 1.0709x over previous
//
#include <hip/hip_runtime.h>

#define CDIV(a,b) (((a)+(b)-1)/(b))

typedef short short8v __attribute__((ext_vector_type(8)));
typedef float f32x4 __attribute__((ext_vector_type(4)));

__device__ __forceinline__ ushort f2bf(float v) {
    uint u = __float_as_uint(v);
    return (ushort)((u + 0x7FFF + ((u >> 16) & 1)) >> 16);
}

// ---------------------------------------------------------------------------
// conv0: 3->96, 64x64 -> 32x32, fully unrolled
// ---------------------------------------------------------------------------
__global__ __launch_bounds__(256) void conv3x3_c3(const float* __restrict__ in,
    const float* __restrict__ w, const float* __restrict__ bias, float* __restrict__ out)
{
    int idx = blockIdx.x * 256 + threadIdx.x;     // 10*96*32*32 = 983040 exact
    int ox = idx & 31; int t = idx >> 5;
    int oy = t & 31;   t >>= 5;
    int co = t % 96;   int b = t / 96;
    float acc = bias[co];
    const float* wp  = w + co * 27;
    const float* ipb = in + (size_t)b * 3 * 64 * 64;
    #pragma unroll
    for (int ci = 0; ci < 3; ++ci) {
        #pragma unroll
        for (int ky = 0; ky < 3; ++ky) {
            int iy = 2 * oy + ky;
            #pragma unroll
            for (int kx = 0; kx < 3; ++kx) {
                int ix = 2 * ox + kx;
                if (iy < 64 && ix < 64)
                    acc = fmaf(wp[ci * 9 + ky * 3 + kx], ipb[(ci * 64 + iy) * 64 + ix], acc);
            }
        }
    }
    out[idx] = fmaxf(acc, 0.f);
}

// ---------------------------------------------------------------------------
// conv1: ci-split-K with LDS staging (unchanged)
// ---------------------------------------------------------------------------
template<int CIN,int COUT,int HIN,int WIN,int SPLITS,int CK,int CO_R>
__global__ __launch_bounds__(256) void conv_splitk_big(const float* __restrict__ in,
    const float* __restrict__ w, float* __restrict__ partial)
{
    constexpr int HOUT = HIN/2, WOUT = WIN/2;
    constexpr int SP = HOUT * WOUT;
    static_assert(SP == 256, "one output px per thread");
    constexpr int HP = HIN + 1, WP = WIN + 2;
    constexpr int CSL = CIN / SPLITS;
    constexpr int NCH = CSL / CK;
    static_assert(CSL % CK == 0, "CK must divide ci slice");
    constexpr int SELEM = CK * HP * WP;
    constexpr int NLD = (SELEM + 255) / 256;
    __shared__ float sb[SELEM];

    const int b = blockIdx.y, s = blockIdx.z;
    const int co_base = blockIdx.x * CO_R;
    const int oy = threadIdx.x >> 4, ox = threadIdx.x & 15;
    const int ci00 = s * CSL;
    const float* inb = in + (size_t)b * CIN * HIN * WIN;

    float rg[NLD];
    auto load_chunk = [&](int ci0) {
        #pragma unroll
        for (int j = 0; j < NLD; ++j) {
            int i = threadIdx.x + j * 256;
            float v = 0.f;
            if (i < SELEM) {
                int c = i % WP; int r = (i / WP) % HP; int cl = i / (WP * HP);
                if (r < HIN && c < WIN) v = inb[((size_t)(ci0 + cl) * HIN + r) * WIN + c];
            }
            rg[j] = v;
        }
    };
    load_chunk(ci00);

    float acc[CO_R] = {};
    for (int ch = 0; ch < NCH; ++ch) {
        #pragma unroll
        for (int j = 0; j < NLD; ++j) {
            int i = threadIdx.x + j * 256;
            if (i < SELEM) sb[i] = rg[j];
        }
        __syncthreads();
        if (ch + 1 < NCH) load_chunk(ci00 + (ch + 1) * CK);

        #pragma unroll
        for (int cl = 0; cl < CK; ++cl) {
            const float* sp = &sb[(cl * HP + 2 * oy) * WP + 2 * ox];
            float x[3][3];
            #pragma unroll
            for (int dy = 0; dy < 3; ++dy) {
                float2 f = *(const float2*)&sp[dy * WP];
                x[dy][0] = f.x; x[dy][1] = f.y; x[dy][2] = sp[dy * WP + 2];
            }
            int ci = ci00 + ch * CK + cl;
            const float* wp = w + ((size_t)co_base * CIN + ci) * 9;
            #pragma unroll
            for (int r = 0; r < CO_R; ++r) {
                const float* wr = wp + (size_t)r * CIN * 9;
                #pragma unroll
                for (int dy = 0; dy < 3; ++dy)
                    #pragma unroll
                    for (int dx = 0; dx < 3; ++dx)
                        acc[r] = fmaf(wr[dy * 3 + dx], x[dy][dx], acc[r]);
            }
        }
        __syncthreads();
    }
    #pragma unroll
    for (int r = 0; r < CO_R; ++r)
        partial[(((size_t)s * 10 + b) * COUT + co_base + r) * SP + threadIdx.x] = acc[r];
}

// ---------------------------------------------------------------------------
// conv2/conv3 split-K (unchanged)
// ---------------------------------------------------------------------------
template<int CIN,int COUT,int HIN,int WIN,int CK,int CO_R,int COS>
__global__ __launch_bounds__(256) void conv_small_splitk(const float* __restrict__ in,
    const float* __restrict__ w, float* __restrict__ partial)
{
    constexpr int HOUT = HIN/2, WOUT = WIN/2;
    constexpr int SP = HOUT * WOUT;
    static_assert(SP * COS == 256, "block covers SP x COS");
    constexpr int HP = HIN + 1, WP = WIN + 2;
    __shared__ float sb[CK * HP * WP];
    const int b = blockIdx.y;
    const int s = blockIdx.z;
    const int sp_i = threadIdx.x % SP;
    const int slot = threadIdx.x / SP;
    const int co_base = (blockIdx.x * COS + slot) * CO_R;
    const int oy = sp_i / WOUT, ox = sp_i % WOUT;
    const int ci0 = s * CK;
    const float* inb = in + (size_t)b * CIN * HIN * WIN;

    for (int i = threadIdx.x; i < CK * HP * WP; i += 256) {
        int c = i % WP; int r = (i / WP) % HP; int cl = i / (WP * HP);
        float v = 0.f;
        if (r < HIN && c < WIN) v = inb[((size_t)(ci0 + cl) * HIN + r) * WIN + c];
        sb[i] = v;
    }
    __syncthreads();

    float acc[CO_R] = {};
    #pragma unroll
    for (int cl = 0; cl < CK; ++cl) {
        const float* sp = &sb[(cl * HP + 2 * oy) * WP + 2 * ox];
        float x[3][3];
        #pragma unroll
        for (int dy = 0; dy < 3; ++dy) {
            float2 f = *(const float2*)&sp[dy * WP];
            x[dy][0] = f.x; x[dy][1] = f.y; x[dy][2] = sp[dy * WP + 2];
        }
        const float* wp = w + ((size_t)co_base * CIN + (ci0 + cl)) * 9;
        #pragma unroll
        for (int r = 0; r < CO_R; ++r) {
            const float* wr = wp + (size_t)r * CIN * 9;
            #pragma unroll
            for (int dy = 0; dy < 3; ++dy)
                #pragma unroll
                for (int dx = 0; dx < 3; ++dx)
                    acc[r] = fmaf(wr[dy * 3 + dx], x[dy][dx], acc[r]);
        }
    }
    #pragma unroll
    for (int r = 0; r < CO_R; ++r)
        partial[(((size_t)s * 10 + b) * COUT + co_base + r) * SP + sp_i] = acc[r];
}

template<int COUT,int SP,int S>
__global__ void conv_reduce_relu(const float* __restrict__ partial, const float* __restrict__ bias,
                                 float* __restrict__ out, int total)
{
    int i = blockIdx.x * 256 + threadIdx.x;
    if (i >= total) return;
    int sp = i % SP; int co = (i / SP) % COUT; int b = i / (SP * COUT);
    float acc = bias[co];
    #pragma unroll
    for (int s = 0; s < S; ++s) acc += partial[(((size_t)s * 10 + b) * COUT + co) * SP + sp];
    out[i] = fmaxf(acc, 0.f);
}

// ---------------------------------------------------------------------------
// d0/d1 split-K quad (unchanged)
// ---------------------------------------------------------------------------
template<int CIN,int COUT,int HIN,int CK,int CO_R,int QPW>
__global__ __launch_bounds__(256) void deconv_quad_splitk(const float* __restrict__ in,
    const float* __restrict__ w, float* __restrict__ partial)
{
    constexpr int CPW = 64 / QPW;
    constexpr int HP2 = HIN + 2;
    constexpr int SP = 4 * HIN * HIN;
    constexpr int WOUT = 2 * HIN;
    static_assert(QPW == HIN * HIN, "wave quads cover input plane");
    __shared__ float sb[CK * HP2 * HP2];
    const int b = blockIdx.y, s = blockIdx.z;
    const int lane = threadIdx.x & 63;
    const int wv = threadIdx.x >> 6;
    const int q = lane % QPW;
    const int co_off = lane / QPW;
    const int t = q / HIN, u = q % HIN;
    const int co_base = (blockIdx.x * 4 + wv) * CPW * CO_R + co_off * CO_R;
    const int ci0 = s * CK;
    const float* inb = in + (size_t)b * CIN * HIN * HIN;

    for (int i = threadIdx.x; i < CK * HP2 * HP2; i += 256) {
        int c = i % HP2; int r = (i / HP2) % HP2; int cl = i / (HP2 * HP2);
        int gr = r - 1, gc = c - 1;
        float v = 0.f;
        if (gr >= 0 && gr < HIN && gc >= 0 && gc < HIN)
            v = inb[((size_t)(ci0 + cl) * HIN + gr) * HIN + gc];
        sb[i] = v;
    }
    __syncthreads();

    float acc[CO_R][4] = {};
    #pragma unroll 4
    for (int cl = 0; cl < CK; ++cl) {
        const float* sp = &sb[(cl * HP2 + t) * HP2 + u];
        float x00 = sp[0],       x01 = sp[1],       x02 = sp[2];
        float x10 = sp[HP2],     x11 = sp[HP2+1],   x12 = sp[HP2+2];
        float x20 = sp[2*HP2],   x21 = sp[2*HP2+1], x22 = sp[2*HP2+2];
        const float* wp = w + ((size_t)(ci0 + cl) * COUT + co_base) * 16;
        #pragma unroll
        for (int r = 0; r < CO_R; ++r) {
            const float* W_ = wp + r * 16;
            acc[r][0] += W_[5]*x11 + W_[7]*x10 + W_[13]*x01 + W_[15]*x00;
            acc[r][1] += W_[4]*x12 + W_[6]*x11 + W_[12]*x02 + W_[14]*x01;
            acc[r][2] += W_[1]*x21 + W_[3]*x20 + W_[9]*x11  + W_[11]*x10;
            acc[r][3] += W_[0]*x22 + W_[2]*x21 + W_[8]*x12  + W_[10]*x11;
        }
    }
    #pragma unroll
    for (int r = 0; r < CO_R; ++r) {
        float* pp = partial + (((size_t)s * 10 + b) * COUT + co_base + r) * SP;
        pp[(2*t)   * WOUT + 2*u]     = acc[r][0];
        pp[(2*t)   * WOUT + 2*u + 1] = acc[r][1];
        pp[(2*t+1) * WOUT + 2*u]     = acc[r][2];
        pp[(2*t+1) * WOUT + 2*u + 1] = acc[r][3];
    }
}

// ---------------------------------------------------------------------------
// Generalized MFMA deconv prep (unchanged mapping)
// ---------------------------------------------------------------------------
template<int CIN,int COUT>
__global__ __launch_bounds__(256) void prep_wA_g(const float* __restrict__ w, ushort* __restrict__ Abuf)
{
    constexpr int MFR = COUT / 16, NSL = CIN / 8;
    constexpr int TOTAL = 4 * MFR * NSL * 64 * 8;
    int idx = blockIdx.x * 256 + threadIdx.x;
    if (idx >= TOTAL) return;
    int e = idx & 7; int t2 = idx >> 3;
    int lane = t2 & 63; t2 >>= 6;
    int s = t2 % NSL; t2 /= NSL;
    int m = t2 % MFR; int q = t2 / MFR;
    int co = m * 16 + (lane & 15);
    int k = s * 32 + (lane >> 4) * 8 + e;
    int tap = k / CIN, ci = k % CIN;
    const int widx[4][4] = {{5,7,13,15},{4,6,12,14},{1,3,9,11},{0,2,8,10}};
    float v = w[((size_t)ci * COUT + co) * 16 + widx[q][tap]];
    Abuf[idx] = f2bf(v);
}

// Generalized MFMA deconv main, now with m-split MS: blockIdx.z = zq + (4/QPB)*ms,
// block computes m-frags [ms*MFR/MS, (ms+1)*MFR/MS).
template<int CIN,int COUT,int HIN,int QPB,int MS>
__global__ __launch_bounds__(256) void deconv_mfma_g(const float* __restrict__ X,
    const ushort* __restrict__ Abuf, const float* __restrict__ bias, float* __restrict__ out)
{
    constexpr int MFR = COUT / 16, NSL = CIN / 8, STR = CIN + 8;
    constexpr int MPB = MFR / MS;
    constexpr int ZQ = 4 / QPB;
    constexpr int WOUT = 2 * HIN, PLANE = 4 * HIN * HIN;
    __shared__ __align__(16) ushort Xs[100 * STR];
    __shared__ float sbias[COUT];
    const int tid = threadIdx.x;
    constexpr int TW = HIN / 8;
    const int t0 = (blockIdx.x / TW) * 8, u0 = (blockIdx.x % TW) * 8;
    const int b = blockIdx.y;
    const int zq = blockIdx.z % ZQ;
    const int ms = blockIdx.z / ZQ;

    const float* Xb = X + (size_t)b * CIN * HIN * HIN;
    for (int i = tid; i < CIN * 100; i += 256) {
        int ci = i / 100, p = i % 100;
        int r = p / 10, c = p % 10;
        int gt = t0 - 1 + r, gu = u0 - 1 + c;
        float v = 0.f;
        if (gt >= 0 && gt < HIN && gu >= 0 && gu < HIN)
            v = Xb[((size_t)ci * HIN + gt) * HIN + gu];
        Xs[p * STR + ci] = f2bf(v);
    }
    if (tid < COUT) sbias[tid] = bias[tid];
    __syncthreads();

    const int w = tid >> 6, lane = tid & 63;
    const int ncol = lane & 15, kg = lane >> 4;
    const int r_n = 2 * w + (ncol >> 3), c_n = ncol & 7;

    #pragma unroll
    for (int qz = 0; qz < QPB; ++qz) {
        const int q = zq * QPB + qz;
        const int py = q >> 1, px = q & 1;
        int ptap[4];
        #pragma unroll
        for (int tp = 0; tp < 4; ++tp) {
            int dy = py - (tp >> 1);
            int dx = px - (tp & 1);
            ptap[tp] = ((r_n + 1 + dy) * 10 + (c_n + 1 + dx)) * STR;
        }
        #pragma unroll
        for (int mm = 0; mm < MPB; ++mm) {
            const int m = ms * MPB + mm;
            f32x4 acc = {0.f, 0.f, 0.f, 0.f};
            const ushort* ab = Abuf + (((size_t)(q * MFR + m) * NSL) * 64 + lane) * 8;
            #pragma unroll
            for (int s = 0; s < NSL; ++s) {
                short8v a = *(const short8v*)(ab + (size_t)s * 64 * 8);
                int tap = (s * 32) / CIN;
                int ci0 = (s * 32) % CIN + kg * 8;
                short8v bf = *(const short8v*)(&Xs[ptap[tap] + ci0]);
                acc = __builtin_amdgcn_mfma_f32_16x16x32_bf16(a, bf, acc, 0, 0, 0);
            }
            int t = t0 + r_n, u = u0 + c_n;
            size_t base = ((size_t)(b * COUT + m * 16 + kg * 4) * (2 * HIN) + (2 * t + py)) * WOUT + (2 * u + px);
            #pragma unroll
            for (int jj = 0; jj < 4; ++jj) {
                float v = acc[jj] + sbias[m * 16 + kg * 4 + jj];
                out[base + (size_t)jj * PLANE] = fmaxf(v, 0.f);
            }
        }
    }
}

// ---------------------------------------------------------------------------
// Split-K FC (unchanged)
// ---------------------------------------------------------------------------
template<int KC>
__global__ __launch_bounds__(256) void fc_splitk(const float* __restrict__ in,
    const float* __restrict__ W, float* __restrict__ partial, int K, int N)
{
    __shared__ float s_in[10 * KC];
    const int o = blockIdx.x * 256 + threadIdx.x;
    const int k0 = blockIdx.y * KC;
    for (int i = threadIdx.x; i < 10 * KC; i += 256) {
        int b = i / KC, k = i % KC;
        s_in[i] = in[(size_t)b * K + k0 + k];
    }
    __syncthreads();

    float acc[10];
    #pragma unroll
    for (int b = 0; b < 10; ++b) acc[b] = 0.f;
    const float* wp = W + (size_t)k0 * N + o;
    #pragma unroll 4
    for (int k = 0; k < KC; ++k) {
        float wv = wp[(size_t)k * N];
        #pragma unroll
        for (int b = 0; b < 10; ++b) acc[b] = fmaf(wv, s_in[b * KC + k], acc[b]);
    }
    float* pp = partial + ((size_t)blockIdx.y * 10) * N + o;
    #pragma unroll
    for (int b = 0; b < 10; ++b) pp[(size_t)b * N] = acc[b];
}

__global__ void fc_reduce_relu(const float* __restrict__ partial, const float* __restrict__ bias,
                               float* __restrict__ out, int N, int S)
{
    int i = blockIdx.x * 256 + threadIdx.x;
    if (i >= 10 * N) return;
    int o = i % N, b = i / N;
    float acc = bias[o];
    for (int s = 0; s < S; ++s) acc += partial[((size_t)s * 10 + b) * N + o];
    out[(size_t)b * N + o] = fmaxf(acc, 0.f);
}

// ---------------------------------------------------------------------------
// Final fused: 1x1 convs + geometry (unchanged)
// ---------------------------------------------------------------------------
__global__ __launch_bounds__(256) void final_fused_v2(const float* __restrict__ h,
    const float* __restrict__ xyzw, const float* __restrict__ xyzb,
    const float* __restrict__ maskw, const float* __restrict__ maskb,
    const float* __restrict__ quat, float* __restrict__ out)
{
    const int V = 8, HW = 128 * 128, C = 48, Bn = 10, VHW = V * HW;
    __shared__ float4 sh[48 * 32];
    int b = blockIdx.y, tile = blockIdx.x;
    const float4* hb = (const float4*)h;
    for (int i = threadIdx.x; i < C * 32; i += 256) {
        int ci = i >> 5, p = i & 31;
        sh[i] = hb[(size_t)(b * C + ci) * (HW / 4) + tile * 32 + p];
    }
    __syncthreads();

    int pl = threadIdx.x & 31, v = threadIdx.x >> 5;
    float4 xr = {0,0,0,0}, yr = {0,0,0,0}, zr = {0,0,0,0}, mm = {0,0,0,0};
    const float* wx = xyzw + (size_t)(v * 3 + 0) * C;
    const float* wy = xyzw + (size_t)(v * 3 + 1) * C;
    const float* wz = xyzw + (size_t)(v * 3 + 2) * C;
    const float* wm = maskw + (size_t)v * C;
    for (int ci = 0; ci < C; ++ci) {
        float4 hv = sh[ci * 32 + pl];
        float a;
        a = wx[ci]; xr.x += a*hv.x; xr.y += a*hv.y; xr.z += a*hv.z; xr.w += a*hv.w;
        a = wy[ci]; yr.x += a*hv.x; yr.y += a*hv.y; yr.z += a*hv.z; yr.w += a*hv.w;
        a = wz[ci]; zr.x += a*hv.x; zr.y += a*hv.y; zr.z += a*hv.z; zr.w += a*hv.w;
        a = wm[ci]; mm.x += a*hv.x; mm.y += a*hv.y; mm.z += a*hv.z; mm.w += a*hv.w;
    }
    float bxv = xyzb[v * 3 + 0], byv = xyzb[v * 3 + 1], bzv = xyzb[v * 3 + 2], bmv = maskb[v];

    float qw = quat[v*4+0], qx = quat[v*4+1], qy = quat[v*4+2], qz = quat[v*4+3];
    float R00 = 1.f - 2.f*(qy*qy + qz*qz), R01 = 2.f*(qx*qy - qw*qz), R02 = 2.f*(qx*qz + qw*qy);
    float R10 = 2.f*(qx*qy + qw*qz), R11 = 1.f - 2.f*(qx*qx + qz*qz), R12 = 2.f*(qy*qz - qw*qx);
    float R20 = 2.f*(qx*qz - qw*qy), R21 = 2.f*(qy*qz + qw*qx), R22 = 1.f - 2.f*(qx*qx + qy*qy);

    float4 o0, o1, o2, om;
    float* X = (float*)&xr; float* Y = (float*)&yr; float* Z = (float*)&zr; float* M = (float*)&mm;
    float* O0 = (float*)&o0; float* O1 = (float*)&o1; float* O2 = (float*)&o2; float* OM = (float*)&om;
    #pragma unroll
    for (int j = 0; j < 4; ++j) {
        float camX = (X[j] + bxv) * (1.f / 64.f) - 0.5f;
        float camY = -(Y[j] + byv) * (1.f / 64.f) + 0.5f;
        float camZ = -((Z[j] + bzv) + 1.0f);
        O0[j] = R00 * camX + R10 * camY + R20 * camZ;
        O1[j] = R01 * camX + R11 * camY + R21 * camZ;
        O2[j] = R02 * camX + R12 * camY + R22 * camZ;
        OM[j] = M[j] + bmv;
    }

    size_t o = (size_t)v * HW + tile * 128 + pl * 4;
    float4* op = (float4*)out;
    op[((size_t)(b * 3 + 0) * VHW + o) >> 2] = o0;
    op[((size_t)(b * 3 + 1) * VHW + o) >> 2] = o1;
    op[((size_t)(b * 3 + 2) * VHW + o) >> 2] = o2;
    op[((size_t)Bn * 3 * VHW + (size_t)b * VHW + o) >> 2] = om;
}

// ---------------------------------------------------------------------------

extern "C" void kernel_launch(void* const* d_in, const int* in_sizes, int n_in,
                              void* d_out, int out_size, void* d_ws, size_t ws_size,
                              hipStream_t stream)
{
    const float* x    = (const float*)d_in[0];
    const float* ew0  = (const float*)d_in[1];
    const float* eb0  = (const float*)d_in[2];
    const float* ew1  = (const float*)d_in[3];
    const float* eb1  = (const float*)d_in[4];
    const float* ew2  = (const float*)d_in[5];
    const float* eb2  = (const float*)d_in[6];
    const float* ew3  = (const float*)d_in[7];
    const float* eb3  = (const float*)d_in[8];
    const float* efw  = (const float*)d_in[9];
    const float* efb  = (const float*)d_in[10];
    const float* dfw  = (const float*)d_in[11];
    const float* dfb  = (const float*)d_in[12];
    const float* dw0  = (const float*)d_in[13];
    const float* db0  = (const float*)d_in[14];
    const float* dw1  = (const float*)d_in[15];
    const float* db1  = (const float*)d_in[16];
    const float* dw2  = (const float*)d_in[17];
    const float* db2  = (const float*)d_in[18];
    const float* dw3  = (const float*)d_in[19];
    const float* db3  = (const float*)d_in[20];
    const float* dw4  = (const float*)d_in[21];
    const float* db4  = (const float*)d_in[22];
    const float* xyzw = (const float*)d_in[23];
    const float* xyzb = (const float*)d_in[24];
    const float* maskw= (const float*)d_in[25];
    const float* maskb= (const float*)d_in[26];
    const float* quat = (const float*)d_in[27];
    float* out = (float*)d_out;

    float* A   = (float*)d_ws;
    float* Bb  = A + 7864320;
    float* P1  = A;                       // fc1 partials 655,360
    float* L   = A + 1120000;             // latent 5,120 (past Abuf3)
    float* P2  = Bb + 1000000;            // fc2 partials 655,360
    float* H0  = Bb;                      // fc2 out 40,960
    float* PC1 = A + 2000000;             // conv1 partials 5,242,880
    float* PC2 = A + 2000000;             // conv2 partials
    float* PC3 = Bb + 500000;             // conv3 partials
    float* PD0 = A + 2000000;             // d0 partials
    float* PD1 = Bb + 1000000;            // d1 partials
    ushort* Abuf4 = (ushort*)(Bb + 2700000);  // d4 A-frags 49,152 ushorts (96 KB)
    ushort* Abuf3 = (ushort*)(A + 1000000);   // d3 A-frags 98,304 ushorts (192 KB)
    ushort* Abuf2 = (ushort*)(A + 1200000);   // d2 A-frags 196,608 ushorts (384 KB)
                                              // dead zone: conv0 out < 983,040; L at 1,120,000..1,125,120;
                                              // PC1 >= 2,000,000; d2-mfma writes A[0..983,040]; overwritten
                                              // only by d4 (after d2/d3 done)

    const int TB = 256;

    // weight prep (independent of activations)
    prep_wA_g< 64,48><<<192, 256, 0, stream>>>(dw4, Abuf4);
    prep_wA_g< 96,64><<<384, 256, 0, stream>>>(dw3, Abuf3);
    prep_wA_g<128,96><<<768, 256, 0, stream>>>(dw2, Abuf2);

    // encoder
    conv3x3_c3<<<3840, 256, 0, stream>>>(x, ew0, eb0, A);
    conv_splitk_big<96,128,32,32,16,6,16><<<dim3(8,10,16), 256, 0, stream>>>(A, ew1, PC1);
    conv_reduce_relu<128,256,16><<<CDIV(327680,TB), TB, 0, stream>>>(PC1, eb1, Bb, 327680);
    conv_small_splitk<128,192,16,16,16,3,4><<<dim3(16,10,8), 256, 0, stream>>>(Bb, ew2, PC2);
    conv_reduce_relu<192,64,8><<<CDIV(122880,TB), TB, 0, stream>>>(PC2, eb2, A, 122880);
    conv_small_splitk<192,256,8,8,16,1,16><<<dim3(16,10,12), 256, 0, stream>>>(A, ew3, PC3);
    conv_reduce_relu<256,16,12><<<CDIV(40960,TB), TB, 0, stream>>>(PC3, eb3, Bb, 40960);

    // fc
    fc_splitk<32><<<dim3(2, 128), 256, 0, stream>>>(Bb, efw, P1, 4096, 512);
    fc_reduce_relu<<<CDIV(10 * 512, TB), TB, 0, stream>>>(P1, efb, L, 512, 128);
    fc_splitk<32><<<dim3(16, 16), 256, 0, stream>>>(L, dfw, P2, 512, 4096);
    fc_reduce_relu<<<CDIV(10 * 4096, TB), TB, 0, stream>>>(P2, dfb, H0, 4096, 16);

    // decoder
    deconv_quad_splitk<256,192,4,64,1,16><<<dim3(12,10,4), 256, 0, stream>>>(H0, dw0, PD0);
    conv_reduce_relu<192,64,4><<<CDIV(122880,TB), TB, 0, stream>>>(PD0, db0, A, 122880);
    deconv_quad_splitk<192,128,8,48,2,64><<<dim3(16,10,4), 256, 0, stream>>>(A, dw1, PD1);
    conv_reduce_relu<128,256,4><<<CDIV(327680,TB), TB, 0, stream>>>(PD1, db1, Bb, 327680);

    // d2: bf16 MFMA, QPB=1 MS=3 -> z=12, 480 blocks
    deconv_mfma_g<128, 96, 16, 1, 3><<<dim3( 4, 10, 12), 256, 0, stream>>>(Bb, Abuf2, db2, A);
    // d3: bf16 MFMA, QPB=1 MS=1 -> z=4, 640 blocks
    deconv_mfma_g< 96, 64, 32, 1, 1><<<dim3(16, 10,  4), 256, 0, stream>>>(A, Abuf3, db3, Bb);
    // d4: bf16 MFMA, QPB=2 MS=1 -> z=2, 1280 blocks
    deconv_mfma_g< 64, 48, 64, 2, 1><<<dim3(64, 10,  2), 256, 0, stream>>>(Bb, Abuf4, db4, A);

    // fused 1x1 convs + geometry -> d_out
    final_fused_v2<<<dim3(128, 10), 256, 0, stream>>>(A, xyzw, xyzb, maskw, maskb, quat, out);
}

// Round 16
// 318.116 us; speedup vs baseline: 1.3923x; 1.0435x over previous
//
#include <hip/hip_runtime.h>

#define CDIV(a,b) (((a)+(b)-1)/(b))

typedef short short8v __attribute__((ext_vector_type(8)));
typedef float f32x4 __attribute__((ext_vector_type(4)));

__device__ __forceinline__ ushort f2bf(float v) {
    uint u = __float_as_uint(v);
    return (ushort)((u + 0x7FFF + ((u >> 16) & 1)) >> 16);
}

// ---------------------------------------------------------------------------
// conv0: 3->96, 64x64 -> 32x32, fully unrolled
// ---------------------------------------------------------------------------
__global__ __launch_bounds__(256) void conv3x3_c3(const float* __restrict__ in,
    const float* __restrict__ w, const float* __restrict__ bias, float* __restrict__ out)
{
    int idx = blockIdx.x * 256 + threadIdx.x;     // 10*96*32*32 = 983040 exact
    int ox = idx & 31; int t = idx >> 5;
    int oy = t & 31;   t >>= 5;
    int co = t % 96;   int b = t / 96;
    float acc = bias[co];
    const float* wp  = w + co * 27;
    const float* ipb = in + (size_t)b * 3 * 64 * 64;
    #pragma unroll
    for (int ci = 0; ci < 3; ++ci) {
        #pragma unroll
        for (int ky = 0; ky < 3; ++ky) {
            int iy = 2 * oy + ky;
            #pragma unroll
            for (int kx = 0; kx < 3; ++kx) {
                int ix = 2 * ox + kx;
                if (iy < 64 && ix < 64)
                    acc = fmaf(wp[ci * 9 + ky * 3 + kx], ipb[(ci * 64 + iy) * 64 + ix], acc);
            }
        }
    }
    out[idx] = fmaxf(acc, 0.f);
}

// ---------------------------------------------------------------------------
// conv1: ci-split-K with LDS staging (unchanged)
// ---------------------------------------------------------------------------
template<int CIN,int COUT,int HIN,int WIN,int SPLITS,int CK,int CO_R>
__global__ __launch_bounds__(256) void conv_splitk_big(const float* __restrict__ in,
    const float* __restrict__ w, float* __restrict__ partial)
{
    constexpr int HOUT = HIN/2, WOUT = WIN/2;
    constexpr int SP = HOUT * WOUT;
    static_assert(SP == 256, "one output px per thread");
    constexpr int HP = HIN + 1, WP = WIN + 2;
    constexpr int CSL = CIN / SPLITS;
    constexpr int NCH = CSL / CK;
    static_assert(CSL % CK == 0, "CK must divide ci slice");
    constexpr int SELEM = CK * HP * WP;
    constexpr int NLD = (SELEM + 255) / 256;
    __shared__ float sb[SELEM];

    const int b = blockIdx.y, s = blockIdx.z;
    const int co_base = blockIdx.x * CO_R;
    const int oy = threadIdx.x >> 4, ox = threadIdx.x & 15;
    const int ci00 = s * CSL;
    const float* inb = in + (size_t)b * CIN * HIN * WIN;

    float rg[NLD];
    auto load_chunk = [&](int ci0) {
        #pragma unroll
        for (int j = 0; j < NLD; ++j) {
            int i = threadIdx.x + j * 256;
            float v = 0.f;
            if (i < SELEM) {
                int c = i % WP; int r = (i / WP) % HP; int cl = i / (WP * HP);
                if (r < HIN && c < WIN) v = inb[((size_t)(ci0 + cl) * HIN + r) * WIN + c];
            }
            rg[j] = v;
        }
    };
    load_chunk(ci00);

    float acc[CO_R] = {};
    for (int ch = 0; ch < NCH; ++ch) {
        #pragma unroll
        for (int j = 0; j < NLD; ++j) {
            int i = threadIdx.x + j * 256;
            if (i < SELEM) sb[i] = rg[j];
        }
        __syncthreads();
        if (ch + 1 < NCH) load_chunk(ci00 + (ch + 1) * CK);

        #pragma unroll
        for (int cl = 0; cl < CK; ++cl) {
            const float* sp = &sb[(cl * HP + 2 * oy) * WP + 2 * ox];
            float x[3][3];
            #pragma unroll
            for (int dy = 0; dy < 3; ++dy) {
                float2 f = *(const float2*)&sp[dy * WP];
                x[dy][0] = f.x; x[dy][1] = f.y; x[dy][2] = sp[dy * WP + 2];
            }
            int ci = ci00 + ch * CK + cl;
            const float* wp = w + ((size_t)co_base * CIN + ci) * 9;
            #pragma unroll
            for (int r = 0; r < CO_R; ++r) {
                const float* wr = wp + (size_t)r * CIN * 9;
                #pragma unroll
                for (int dy = 0; dy < 3; ++dy)
                    #pragma unroll
                    for (int dx = 0; dx < 3; ++dx)
                        acc[r] = fmaf(wr[dy * 3 + dx], x[dy][dx], acc[r]);
            }
        }
        __syncthreads();
    }
    #pragma unroll
    for (int r = 0; r < CO_R; ++r)
        partial[(((size_t)s * 10 + b) * COUT + co_base + r) * SP + threadIdx.x] = acc[r];
}

// ---------------------------------------------------------------------------
// conv2/conv3 split-K (unchanged)
// ---------------------------------------------------------------------------
template<int CIN,int COUT,int HIN,int WIN,int CK,int CO_R,int COS>
__global__ __launch_bounds__(256) void conv_small_splitk(const float* __restrict__ in,
    const float* __restrict__ w, float* __restrict__ partial)
{
    constexpr int HOUT = HIN/2, WOUT = WIN/2;
    constexpr int SP = HOUT * WOUT;
    static_assert(SP * COS == 256, "block covers SP x COS");
    constexpr int HP = HIN + 1, WP = WIN + 2;
    __shared__ float sb[CK * HP * WP];
    const int b = blockIdx.y;
    const int s = blockIdx.z;
    const int sp_i = threadIdx.x % SP;
    const int slot = threadIdx.x / SP;
    const int co_base = (blockIdx.x * COS + slot) * CO_R;
    const int oy = sp_i / WOUT, ox = sp_i % WOUT;
    const int ci0 = s * CK;
    const float* inb = in + (size_t)b * CIN * HIN * WIN;

    for (int i = threadIdx.x; i < CK * HP * WP; i += 256) {
        int c = i % WP; int r = (i / WP) % HP; int cl = i / (WP * HP);
        float v = 0.f;
        if (r < HIN && c < WIN) v = inb[((size_t)(ci0 + cl) * HIN + r) * WIN + c];
        sb[i] = v;
    }
    __syncthreads();

    float acc[CO_R] = {};
    #pragma unroll
    for (int cl = 0; cl < CK; ++cl) {
        const float* sp = &sb[(cl * HP + 2 * oy) * WP + 2 * ox];
        float x[3][3];
        #pragma unroll
        for (int dy = 0; dy < 3; ++dy) {
            float2 f = *(const float2*)&sp[dy * WP];
            x[dy][0] = f.x; x[dy][1] = f.y; x[dy][2] = sp[dy * WP + 2];
        }
        const float* wp = w + ((size_t)co_base * CIN + (ci0 + cl)) * 9;
        #pragma unroll
        for (int r = 0; r < CO_R; ++r) {
            const float* wr = wp + (size_t)r * CIN * 9;
            #pragma unroll
            for (int dy = 0; dy < 3; ++dy)
                #pragma unroll
                for (int dx = 0; dx < 3; ++dx)
                    acc[r] = fmaf(wr[dy * 3 + dx], x[dy][dx], acc[r]);
        }
    }
    #pragma unroll
    for (int r = 0; r < CO_R; ++r)
        partial[(((size_t)s * 10 + b) * COUT + co_base + r) * SP + sp_i] = acc[r];
}

template<int COUT,int SP,int S>
__global__ void conv_reduce_relu(const float* __restrict__ partial, const float* __restrict__ bias,
                                 float* __restrict__ out, int total)
{
    int i = blockIdx.x * 256 + threadIdx.x;
    if (i >= total) return;
    int sp = i % SP; int co = (i / SP) % COUT; int b = i / (SP * COUT);
    float acc = bias[co];
    #pragma unroll
    for (int s = 0; s < S; ++s) acc += partial[(((size_t)s * 10 + b) * COUT + co) * SP + sp];
    out[i] = fmaxf(acc, 0.f);
}

// ---------------------------------------------------------------------------
// d0 split-K quad (unchanged; d0 only now)
// ---------------------------------------------------------------------------
template<int CIN,int COUT,int HIN,int CK,int CO_R,int QPW>
__global__ __launch_bounds__(256) void deconv_quad_splitk(const float* __restrict__ in,
    const float* __restrict__ w, float* __restrict__ partial)
{
    constexpr int CPW = 64 / QPW;
    constexpr int HP2 = HIN + 2;
    constexpr int SP = 4 * HIN * HIN;
    constexpr int WOUT = 2 * HIN;
    static_assert(QPW == HIN * HIN, "wave quads cover input plane");
    __shared__ float sb[CK * HP2 * HP2];
    const int b = blockIdx.y, s = blockIdx.z;
    const int lane = threadIdx.x & 63;
    const int wv = threadIdx.x >> 6;
    const int q = lane % QPW;
    const int co_off = lane / QPW;
    const int t = q / HIN, u = q % HIN;
    const int co_base = (blockIdx.x * 4 + wv) * CPW * CO_R + co_off * CO_R;
    const int ci0 = s * CK;
    const float* inb = in + (size_t)b * CIN * HIN * HIN;

    for (int i = threadIdx.x; i < CK * HP2 * HP2; i += 256) {
        int c = i % HP2; int r = (i / HP2) % HP2; int cl = i / (HP2 * HP2);
        int gr = r - 1, gc = c - 1;
        float v = 0.f;
        if (gr >= 0 && gr < HIN && gc >= 0 && gc < HIN)
            v = inb[((size_t)(ci0 + cl) * HIN + gr) * HIN + gc];
        sb[i] = v;
    }
    __syncthreads();

    float acc[CO_R][4] = {};
    #pragma unroll 4
    for (int cl = 0; cl < CK; ++cl) {
        const float* sp = &sb[(cl * HP2 + t) * HP2 + u];
        float x00 = sp[0],       x01 = sp[1],       x02 = sp[2];
        float x10 = sp[HP2],     x11 = sp[HP2+1],   x12 = sp[HP2+2];
        float x20 = sp[2*HP2],   x21 = sp[2*HP2+1], x22 = sp[2*HP2+2];
        const float* wp = w + ((size_t)(ci0 + cl) * COUT + co_base) * 16;
        #pragma unroll
        for (int r = 0; r < CO_R; ++r) {
            const float* W_ = wp + r * 16;
            acc[r][0] += W_[5]*x11 + W_[7]*x10 + W_[13]*x01 + W_[15]*x00;
            acc[r][1] += W_[4]*x12 + W_[6]*x11 + W_[12]*x02 + W_[14]*x01;
            acc[r][2] += W_[1]*x21 + W_[3]*x20 + W_[9]*x11  + W_[11]*x10;
            acc[r][3] += W_[0]*x22 + W_[2]*x21 + W_[8]*x12  + W_[10]*x11;
        }
    }
    #pragma unroll
    for (int r = 0; r < CO_R; ++r) {
        float* pp = partial + (((size_t)s * 10 + b) * COUT + co_base + r) * SP;
        pp[(2*t)   * WOUT + 2*u]     = acc[r][0];
        pp[(2*t)   * WOUT + 2*u + 1] = acc[r][1];
        pp[(2*t+1) * WOUT + 2*u]     = acc[r][2];
        pp[(2*t+1) * WOUT + 2*u + 1] = acc[r][3];
    }
}

// ---------------------------------------------------------------------------
// Generalized MFMA deconv prep (unchanged mapping)
// ---------------------------------------------------------------------------
template<int CIN,int COUT>
__global__ __launch_bounds__(256) void prep_wA_g(const float* __restrict__ w, ushort* __restrict__ Abuf)
{
    constexpr int MFR = COUT / 16, NSL = CIN / 8;
    constexpr int TOTAL = 4 * MFR * NSL * 64 * 8;
    int idx = blockIdx.x * 256 + threadIdx.x;
    if (idx >= TOTAL) return;
    int e = idx & 7; int t2 = idx >> 3;
    int lane = t2 & 63; t2 >>= 6;
    int s = t2 % NSL; t2 /= NSL;
    int m = t2 % MFR; int q = t2 / MFR;
    int co = m * 16 + (lane & 15);
    int k = s * 32 + (lane >> 4) * 8 + e;
    int tap = k / CIN, ci = k % CIN;
    const int widx[4][4] = {{5,7,13,15},{4,6,12,14},{1,3,9,11},{0,2,8,10}};
    float v = w[((size_t)ci * COUT + co) * 16 + widx[q][tap]];
    Abuf[idx] = f2bf(v);
}

// Generalized MFMA deconv main with m-split MS: blockIdx.z = zq + (4/QPB)*ms.
template<int CIN,int COUT,int HIN,int QPB,int MS>
__global__ __launch_bounds__(256) void deconv_mfma_g(const float* __restrict__ X,
    const ushort* __restrict__ Abuf, const float* __restrict__ bias, float* __restrict__ out)
{
    constexpr int MFR = COUT / 16, NSL = CIN / 8, STR = CIN + 8;
    constexpr int MPB = MFR / MS;
    constexpr int ZQ = 4 / QPB;
    constexpr int WOUT = 2 * HIN, PLANE = 4 * HIN * HIN;
    __shared__ __align__(16) ushort Xs[100 * STR];
    __shared__ float sbias[COUT];
    const int tid = threadIdx.x;
    constexpr int TW = HIN / 8;
    const int t0 = (blockIdx.x / TW) * 8, u0 = (blockIdx.x % TW) * 8;
    const int b = blockIdx.y;
    const int zq = blockIdx.z % ZQ;
    const int ms = blockIdx.z / ZQ;

    const float* Xb = X + (size_t)b * CIN * HIN * HIN;
    for (int i = tid; i < CIN * 100; i += 256) {
        int ci = i / 100, p = i % 100;
        int r = p / 10, c = p % 10;
        int gt = t0 - 1 + r, gu = u0 - 1 + c;
        float v = 0.f;
        if (gt >= 0 && gt < HIN && gu >= 0 && gu < HIN)
            v = Xb[((size_t)ci * HIN + gt) * HIN + gu];
        Xs[p * STR + ci] = f2bf(v);
    }
    if (tid < COUT) sbias[tid] = bias[tid];
    __syncthreads();

    const int w = tid >> 6, lane = tid & 63;
    const int ncol = lane & 15, kg = lane >> 4;
    const int r_n = 2 * w + (ncol >> 3), c_n = ncol & 7;

    #pragma unroll
    for (int qz = 0; qz < QPB; ++qz) {
        const int q = zq * QPB + qz;
        const int py = q >> 1, px = q & 1;
        int ptap[4];
        #pragma unroll
        for (int tp = 0; tp < 4; ++tp) {
            int dy = py - (tp >> 1);
            int dx = px - (tp & 1);
            ptap[tp] = ((r_n + 1 + dy) * 10 + (c_n + 1 + dx)) * STR;
        }
        #pragma unroll
        for (int mm = 0; mm < MPB; ++mm) {
            const int m = ms * MPB + mm;
            f32x4 acc = {0.f, 0.f, 0.f, 0.f};
            const ushort* ab = Abuf + (((size_t)(q * MFR + m) * NSL) * 64 + lane) * 8;
            #pragma unroll
            for (int s = 0; s < NSL; ++s) {
                short8v a = *(const short8v*)(ab + (size_t)s * 64 * 8);
                int tap = (s * 32) / CIN;
                int ci0 = (s * 32) % CIN + kg * 8;
                short8v bf = *(const short8v*)(&Xs[ptap[tap] + ci0]);
                acc = __builtin_amdgcn_mfma_f32_16x16x32_bf16(a, bf, acc, 0, 0, 0);
            }
            int t = t0 + r_n, u = u0 + c_n;
            size_t base = ((size_t)(b * COUT + m * 16 + kg * 4) * (2 * HIN) + (2 * t + py)) * WOUT + (2 * u + px);
            #pragma unroll
            for (int jj = 0; jj < 4; ++jj) {
                float v = acc[jj] + sbias[m * 16 + kg * 4 + jj];
                out[base + (size_t)jj * PLANE] = fmaxf(v, 0.f);
            }
        }
    }
}

// ---------------------------------------------------------------------------
// Split-K FC (unchanged)
// ---------------------------------------------------------------------------
template<int KC>
__global__ __launch_bounds__(256) void fc_splitk(const float* __restrict__ in,
    const float* __restrict__ W, float* __restrict__ partial, int K, int N)
{
    __shared__ float s_in[10 * KC];
    const int o = blockIdx.x * 256 + threadIdx.x;
    const int k0 = blockIdx.y * KC;
    for (int i = threadIdx.x; i < 10 * KC; i += 256) {
        int b = i / KC, k = i % KC;
        s_in[i] = in[(size_t)b * K + k0 + k];
    }
    __syncthreads();

    float acc[10];
    #pragma unroll
    for (int b = 0; b < 10; ++b) acc[b] = 0.f;
    const float* wp = W + (size_t)k0 * N + o;
    #pragma unroll 4
    for (int k = 0; k < KC; ++k) {
        float wv = wp[(size_t)k * N];
        #pragma unroll
        for (int b = 0; b < 10; ++b) acc[b] = fmaf(wv, s_in[b * KC + k], acc[b]);
    }
    float* pp = partial + ((size_t)blockIdx.y * 10) * N + o;
    #pragma unroll
    for (int b = 0; b < 10; ++b) pp[(size_t)b * N] = acc[b];
}

__global__ void fc_reduce_relu(const float* __restrict__ partial, const float* __restrict__ bias,
                               float* __restrict__ out, int N, int S)
{
    int i = blockIdx.x * 256 + threadIdx.x;
    if (i >= 10 * N) return;
    int o = i % N, b = i / N;
    float acc = bias[o];
    for (int s = 0; s < S; ++s) acc += partial[((size_t)s * 10 + b) * N + o];
    out[(size_t)b * N + o] = fmaxf(acc, 0.f);
}

// ---------------------------------------------------------------------------
// Final fused: 1x1 convs + geometry (unchanged)
// ---------------------------------------------------------------------------
__global__ __launch_bounds__(256) void final_fused_v2(const float* __restrict__ h,
    const float* __restrict__ xyzw, const float* __restrict__ xyzb,
    const float* __restrict__ maskw, const float* __restrict__ maskb,
    const float* __restrict__ quat, float* __restrict__ out)
{
    const int V = 8, HW = 128 * 128, C = 48, Bn = 10, VHW = V * HW;
    __shared__ float4 sh[48 * 32];
    int b = blockIdx.y, tile = blockIdx.x;
    const float4* hb = (const float4*)h;
    for (int i = threadIdx.x; i < C * 32; i += 256) {
        int ci = i >> 5, p = i & 31;
        sh[i] = hb[(size_t)(b * C + ci) * (HW / 4) + tile * 32 + p];
    }
    __syncthreads();

    int pl = threadIdx.x & 31, v = threadIdx.x >> 5;
    float4 xr = {0,0,0,0}, yr = {0,0,0,0}, zr = {0,0,0,0}, mm = {0,0,0,0};
    const float* wx = xyzw + (size_t)(v * 3 + 0) * C;
    const float* wy = xyzw + (size_t)(v * 3 + 1) * C;
    const float* wz = xyzw + (size_t)(v * 3 + 2) * C;
    const float* wm = maskw + (size_t)v * C;
    for (int ci = 0; ci < C; ++ci) {
        float4 hv = sh[ci * 32 + pl];
        float a;
        a = wx[ci]; xr.x += a*hv.x; xr.y += a*hv.y; xr.z += a*hv.z; xr.w += a*hv.w;
        a = wy[ci]; yr.x += a*hv.x; yr.y += a*hv.y; yr.z += a*hv.z; yr.w += a*hv.w;
        a = wz[ci]; zr.x += a*hv.x; zr.y += a*hv.y; zr.z += a*hv.z; zr.w += a*hv.w;
        a = wm[ci]; mm.x += a*hv.x; mm.y += a*hv.y; mm.z += a*hv.z; mm.w += a*hv.w;
    }
    float bxv = xyzb[v * 3 + 0], byv = xyzb[v * 3 + 1], bzv = xyzb[v * 3 + 2], bmv = maskb[v];

    float qw = quat[v*4+0], qx = quat[v*4+1], qy = quat[v*4+2], qz = quat[v*4+3];
    float R00 = 1.f - 2.f*(qy*qy + qz*qz), R01 = 2.f*(qx*qy - qw*qz), R02 = 2.f*(qx*qz + qw*qy);
    float R10 = 2.f*(qx*qy + qw*qz), R11 = 1.f - 2.f*(qx*qx + qz*qz), R12 = 2.f*(qy*qz - qw*qx);
    float R20 = 2.f*(qx*qz - qw*qy), R21 = 2.f*(qy*qz + qw*qx), R22 = 1.f - 2.f*(qx*qx + qy*qy);

    float4 o0, o1, o2, om;
    float* X = (float*)&xr; float* Y = (float*)&yr; float* Z = (float*)&zr; float* M = (float*)&mm;
    float* O0 = (float*)&o0; float* O1 = (float*)&o1; float* O2 = (float*)&o2; float* OM = (float*)&om;
    #pragma unroll
    for (int j = 0; j < 4; ++j) {
        float camX = (X[j] + bxv) * (1.f / 64.f) - 0.5f;
        float camY = -(Y[j] + byv) * (1.f / 64.f) + 0.5f;
        float camZ = -((Z[j] + bzv) + 1.0f);
        O0[j] = R00 * camX + R10 * camY + R20 * camZ;
        O1[j] = R01 * camX + R11 * camY + R21 * camZ;
        O2[j] = R02 * camX + R12 * camY + R22 * camZ;
        OM[j] = M[j] + bmv;
    }

    size_t o = (size_t)v * HW + tile * 128 + pl * 4;
    float4* op = (float4*)out;
    op[((size_t)(b * 3 + 0) * VHW + o) >> 2] = o0;
    op[((size_t)(b * 3 + 1) * VHW + o) >> 2] = o1;
    op[((size_t)(b * 3 + 2) * VHW + o) >> 2] = o2;
    op[((size_t)Bn * 3 * VHW + (size_t)b * VHW + o) >> 2] = om;
}

// ---------------------------------------------------------------------------

extern "C" void kernel_launch(void* const* d_in, const int* in_sizes, int n_in,
                              void* d_out, int out_size, void* d_ws, size_t ws_size,
                              hipStream_t stream)
{
    const float* x    = (const float*)d_in[0];
    const float* ew0  = (const float*)d_in[1];
    const float* eb0  = (const float*)d_in[2];
    const float* ew1  = (const float*)d_in[3];
    const float* eb1  = (const float*)d_in[4];
    const float* ew2  = (const float*)d_in[5];
    const float* eb2  = (const float*)d_in[6];
    const float* ew3  = (const float*)d_in[7];
    const float* eb3  = (const float*)d_in[8];
    const float* efw  = (const float*)d_in[9];
    const float* efb  = (const float*)d_in[10];
    const float* dfw  = (const float*)d_in[11];
    const float* dfb  = (const float*)d_in[12];
    const float* dw0  = (const float*)d_in[13];
    const float* db0  = (const float*)d_in[14];
    const float* dw1  = (const float*)d_in[15];
    const float* db1  = (const float*)d_in[16];
    const float* dw2  = (const float*)d_in[17];
    const float* db2  = (const float*)d_in[18];
    const float* dw3  = (const float*)d_in[19];
    const float* db3  = (const float*)d_in[20];
    const float* dw4  = (const float*)d_in[21];
    const float* db4  = (const float*)d_in[22];
    const float* xyzw = (const float*)d_in[23];
    const float* xyzb = (const float*)d_in[24];
    const float* maskw= (const float*)d_in[25];
    const float* maskb= (const float*)d_in[26];
    const float* quat = (const float*)d_in[27];
    float* out = (float*)d_out;

    float* A   = (float*)d_ws;
    float* Bb  = A + 7864320;
    float* P1  = A;                       // fc1 partials 655,360
    float* L   = A + 1120000;             // latent 5,120
    float* P2  = Bb + 1000000;            // fc2 partials 655,360
    float* H0  = Bb;                      // fc2 out 40,960
    float* PC1 = A + 2000000;             // conv1 partials 5,242,880
    float* PC2 = A + 2000000;             // conv2 partials
    float* PC3 = Bb + 500000;             // conv3 partials
    float* PD0 = A + 2000000;             // d0 partials
    ushort* Abuf4 = (ushort*)(Bb + 2700000);  // d4 A-frags  49,152 ushorts (96 KB)
    ushort* Abuf3 = (ushort*)(A + 1000000);   // d3 A-frags  98,304 ushorts (192 KB)
    ushort* Abuf2 = (ushort*)(A + 1200000);   // d2 A-frags 196,608 ushorts (384 KB)
    ushort* Abuf1 = (ushort*)(A + 1400000);   // d1 A-frags 393,216 ushorts (786 KB)
    // dead-zone audit: conv0 out < 983,040; P1 < 655,360; L at 1,120,000..1,125,120;
    // PC1/PC2/PD0 >= 2,000,000; d2-mfma writes A[0..983,040]; Abufs consumed before
    // d4-mfma overwrites A; Abuf4 lives in Bb past d3's 2,621,440-float output.

    const int TB = 256;

    // weight prep (independent of activations)
    prep_wA_g< 64, 48><<< 192, 256, 0, stream>>>(dw4, Abuf4);
    prep_wA_g< 96, 64><<< 384, 256, 0, stream>>>(dw3, Abuf3);
    prep_wA_g<128, 96><<< 768, 256, 0, stream>>>(dw2, Abuf2);
    prep_wA_g<192,128><<<1536, 256, 0, stream>>>(dw1, Abuf1);

    // encoder
    conv3x3_c3<<<3840, 256, 0, stream>>>(x, ew0, eb0, A);
    conv_splitk_big<96,128,32,32,16,6,16><<<dim3(8,10,16), 256, 0, stream>>>(A, ew1, PC1);
    conv_reduce_relu<128,256,16><<<CDIV(327680,TB), TB, 0, stream>>>(PC1, eb1, Bb, 327680);
    conv_small_splitk<128,192,16,16,16,3,4><<<dim3(16,10,8), 256, 0, stream>>>(Bb, ew2, PC2);
    conv_reduce_relu<192,64,8><<<CDIV(122880,TB), TB, 0, stream>>>(PC2, eb2, A, 122880);
    conv_small_splitk<192,256,8,8,16,1,16><<<dim3(16,10,12), 256, 0, stream>>>(A, ew3, PC3);
    conv_reduce_relu<256,16,12><<<CDIV(40960,TB), TB, 0, stream>>>(PC3, eb3, Bb, 40960);

    // fc
    fc_splitk<32><<<dim3(2, 128), 256, 0, stream>>>(Bb, efw, P1, 4096, 512);
    fc_reduce_relu<<<CDIV(10 * 512, TB), TB, 0, stream>>>(P1, efb, L, 512, 128);
    fc_splitk<32><<<dim3(16, 16), 256, 0, stream>>>(L, dfw, P2, 512, 4096);
    fc_reduce_relu<<<CDIV(10 * 4096, TB), TB, 0, stream>>>(P2, dfb, H0, 4096, 16);

    // decoder
    deconv_quad_splitk<256,192,4,64,1,16><<<dim3(12,10,4), 256, 0, stream>>>(H0, dw0, PD0);
    conv_reduce_relu<192,64,4><<<CDIV(122880,TB), TB, 0, stream>>>(PD0, db0, A, 122880);

    // d1: bf16 MFMA, QPB=1 MS=8 -> z=32, 320 blocks (replaces splitk + reduce)
    deconv_mfma_g<192,128,  8, 1, 8><<<dim3( 1, 10, 32), 256, 0, stream>>>(A, Abuf1, db1, Bb);
    // d2: bf16 MFMA, QPB=1 MS=3 -> z=12, 480 blocks
    deconv_mfma_g<128, 96, 16, 1, 3><<<dim3( 4, 10, 12), 256, 0, stream>>>(Bb, Abuf2, db2, A);
    // d3: bf16 MFMA, QPB=1 MS=1 -> z=4, 640 blocks
    deconv_mfma_g< 96, 64, 32, 1, 1><<<dim3(16, 10,  4), 256, 0, stream>>>(A, Abuf3, db3, Bb);
    // d4: bf16 MFMA, QPB=2 MS=1 -> z=2, 1280 blocks
    deconv_mfma_g< 64, 48, 64, 2, 1><<<dim3(64, 10,  2), 256, 0, stream>>>(Bb, Abuf4, db4, A);

    // fused 1x1 convs + geometry -> d_out
    final_fused_v2<<<dim3(128, 10), 256, 0, stream>>>(A, xyzw, xyzb, maskw, maskb, quat, out);
}